// Round 17
// baseline (3815.416 us; speedup 1.0000x reference)
//
#include <hip/hip_runtime.h>
#include <math.h>

// ---------------------------------------------------------------------------
// CLSADecoder: 2-layer RowSharedConvLSTM + inter-attn + causal self-attn + head
// B=128, T=64, D=2048 (ROWS=8, CH=32, COLS=8), S=128.
// R16: hoist the O(T^2) self-attn score dots out of the serial chain.
// T chunked 4x16: after each selfchain chunk, k_scores computes that chunk's
// r-rows x all future p-rows (r in 67KB LDS, read once per chunk) -> Smat
// (2MB f32). k_selfchain_c reads old scores from Smat, computes <=15 intra
// dots, softmax+G-sum+epilogue as before. Score history traffic 16MB->1.9MB
// per b per layer; redundant per-wave p reads eliminated.
// ---------------------------------------------------------------------------

typedef _Float16 f16;
typedef _Float16 f16x8 __attribute__((ext_vector_type(8)));
typedef _Float16 f16x4 __attribute__((ext_vector_type(4)));
typedef _Float16 f16x2 __attribute__((ext_vector_type(2)));
typedef float  f32x16 __attribute__((ext_vector_type(16)));
typedef float  f32x4v __attribute__((ext_vector_type(4)));
typedef float  f32x2v __attribute__((ext_vector_type(2)));
typedef unsigned short u16x8 __attribute__((ext_vector_type(8)));
typedef unsigned short u16x4 __attribute__((ext_vector_type(4)));

#define BD 262144   // 128*2048  (one [B][D] plane)
#define XGT 1048576 // xg per-t stride: 128*8*1024 elements

__device__ __forceinline__ unsigned short f2bf(float x){
  unsigned int u = __builtin_bit_cast(unsigned int, x);
  u += 0x7fffu + ((u >> 16) & 1u);
  return (unsigned short)(u >> 16);
}
__device__ __forceinline__ float bf2f(unsigned short h){
  unsigned int u = ((unsigned int)h) << 16;
  return __builtin_bit_cast(float, u);
}
__device__ __forceinline__ float sigmoidf_(float x){
  return 1.0f / (1.0f + __expf(-x));
}
__device__ __forceinline__ void g2l16(const void* g, void* l){
  __builtin_amdgcn_global_load_lds(
      (const __attribute__((address_space(1))) unsigned int*)g,
      (__attribute__((address_space(3))) unsigned int*)l,
      16, 0, 0);
}

// ---------------------------------------------------------------------------
// transpose f32 weight [K][N] -> f16 plane [N][K]
// ---------------------------------------------------------------------------
__global__ __launch_bounds__(256) void k_transpose_f16(
    const float* __restrict__ src, f16* __restrict__ dhi,
    const int K, const int N)
{
  __shared__ float tile[32][33];
  const int n0 = blockIdx.x * 32, k0 = blockIdx.y * 32;
  const int tx = threadIdx.x & 31, ty = threadIdx.x >> 5;
  #pragma unroll
  for (int ii = 0; ii < 4; ++ii){
    const int k = k0 + ty + ii*8, n = n0 + tx;
    float v = (n < N) ? src[(size_t)k * N + n] : 0.0f;
    tile[ty + ii*8][tx] = v;
  }
  __syncthreads();
  #pragma unroll
  for (int ii = 0; ii < 4; ++ii){
    const int n = n0 + ty + ii*8, k = k0 + tx;
    dhi[(size_t)n * K + k] = (f16)tile[tx][ty + ii*8];
  }
}

// enc f32 -> encF (f16, [b][s][d]) and encT (f16, [b][d][s])
__global__ __launch_bounds__(256) void k_enc_prep(
    const float* __restrict__ enc,
    f16* __restrict__ encF, f16* __restrict__ encT)
{
  __shared__ float tile[32][33];
  const int dt = blockIdx.x;   // 0..63
  const int st = blockIdx.y;   // 0..3
  const int b  = blockIdx.z;   // 0..127
  const int tx = threadIdx.x & 31, ty = threadIdx.x >> 5;
  const int d0 = dt*32, s0 = st*32;
  #pragma unroll
  for (int ii = 0; ii < 4; ++ii){
    const int s = s0 + ty + ii*8, d = d0 + tx;
    const float v = enc[((size_t)b*128 + s)*2048 + d];
    tile[ty + ii*8][tx] = v;
    encF[((size_t)b*128 + s)*2048 + d] = (f16)v;
  }
  __syncthreads();
  #pragma unroll
  for (int ii = 0; ii < 4; ++ii){
    const int d = d0 + ty + ii*8, s = s0 + tx;
    encT[((size_t)b*2048 + d)*128 + s] = (f16)tile[tx][ty + ii*8];
  }
}

// split cell1 conv weights: wh16[(icg*3+j)*128+gc] (h taps),
// wcx16[(icg*3+j)*128+gc] (x taps), bf16.
__global__ void k_pack_cellw(const float* __restrict__ chw,
                             const float* __restrict__ cxw,
                             unsigned short* __restrict__ wh16,
                             unsigned short* __restrict__ wcx16)
{
  const int i = blockIdx.x * 256 + threadIdx.x;   // i = gc*32 + icg
  if (i < 128 * 32){
    const int gc = i >> 5, icg = i & 31;
    #pragma unroll
    for (int k = 0; k < 3; ++k){
      wh16[(icg*3 + k)*128 + gc]  = f2bf(chw[i*3 + k]);
      wcx16[(icg*3 + k)*128 + gc] = f2bf(cxw[i*3 + k]);
    }
  }
}

// ---------------------------------------------------------------------------
// Layer-0 ConvLSTM for ALL 64 steps. Block=(b,row). Writes hraw hi only.
// ---------------------------------------------------------------------------
__global__ __launch_bounds__(256) void k_cell0(
    const float* __restrict__ x_flat,
    const float* __restrict__ h0, const float* __restrict__ c0,
    const float* __restrict__ cxw, const float* __restrict__ cxb,
    const float* __restrict__ chw, const float* __restrict__ chb,
    f16* __restrict__ hrawHi)     // [T][B][2048]
{
  const int b = blockIdx.x >> 3, row = blockIdx.x & 7;
  const int tid = threadIdx.x;
  __shared__ float h_lds[264];
  __shared__ float x_lds[8];
  __shared__ float P[128][2][9];
  const int gc = tid >> 1, ih = tid & 1;
  float wh[16][3];
  #pragma unroll
  for (int icl = 0; icl < 16; ++icl)
    #pragma unroll
    for (int k = 0; k < 3; ++k)
      wh[icl][k] = chw[(gc*32 + ih*16 + icl)*3 + k];
  const float wx0 = cxw[gc*3+0], wx1 = cxw[gc*3+1], wx2 = cxw[gc*3+2];
  const float bsum = cxb[gc] + chb[gc];
  const int ic = tid >> 3, col = tid & 7;
  const size_t dg = (size_t)b*2048 + row*256 + tid;
  const int wofs = tid + ((tid >> 7) << 2);
  const int hbase = ih * 132;
  float c_reg = c0[dg];
  h_lds[wofs] = h0[dg];
  float xnext = (tid < 8) ? x_flat[((size_t)b*64 + 0)*64 + row*8 + tid] : 0.f;
  __syncthreads();
  for (int t = 0; t < 64; ++t){
    if (tid < 8) x_lds[tid] = xnext;
    __syncthreads();
    if (t < 63 && tid < 8)
      xnext = x_flat[((size_t)b*64 + t + 1)*64 + row*8 + tid];
    float g8[8];
    #pragma unroll
    for (int c2 = 0; c2 < 8; ++c2) g8[c2] = 0.f;
    #pragma unroll
    for (int icl = 0; icl < 16; ++icl){
      const float* hb = &h_lds[icl*8 + hbase];
      f32x4v hv0 = *reinterpret_cast<const f32x4v*>(hb);
      f32x4v hv1 = *reinterpret_cast<const f32x4v*>(hb + 4);
      const float hv[8] = {hv0[0],hv0[1],hv0[2],hv0[3],hv1[0],hv1[1],hv1[2],hv1[3]};
      #pragma unroll
      for (int c2 = 0; c2 < 8; ++c2){
        float s = hv[c2] * wh[icl][1];
        if (c2 > 0) s += hv[c2-1] * wh[icl][0];
        if (c2 < 7) s += hv[c2+1] * wh[icl][2];
        g8[c2] += s;
      }
    }
    if (ih == 0){
      #pragma unroll
      for (int c2 = 0; c2 < 8; ++c2){
        float s = x_lds[c2] * wx1 + bsum;
        if (c2 > 0) s += x_lds[c2-1] * wx0;
        if (c2 < 7) s += x_lds[c2+1] * wx2;
        g8[c2] += s;
      }
    }
    #pragma unroll
    for (int c2 = 0; c2 < 8; ++c2) P[gc][ih][c2] = g8[c2];
    __syncthreads();
    const float ipre = P[ic   ][0][col] + P[ic   ][1][col];
    const float fpre = P[ic+32][0][col] + P[ic+32][1][col];
    const float opre = P[ic+64][0][col] + P[ic+64][1][col];
    const float gpre = P[ic+96][0][col] + P[ic+96][1][col];
    const float cn = sigmoidf_(fpre)*c_reg + sigmoidf_(ipre)*tanhf(gpre);
    c_reg = cn;
    const float hn = sigmoidf_(opre)*tanhf(cn);
    hrawHi[((size_t)t*128 + b)*2048 + row*256 + tid] = (f16)hn;
    __syncthreads();
    h_lds[wofs] = hn;
  }
}

// ---------------------------------------------------------------------------
// Batched x-convolution for layer 1, grid-parallel: block = (b,row, t-chunk
// of 8). All 8 x-rows staged up front, ONE barrier.
// ---------------------------------------------------------------------------
__global__ __launch_bounds__(256) void k_xconv(
    const f16* __restrict__ r0Hi, const f16* __restrict__ r0Lo,
    const unsigned short* __restrict__ wcx16,  // [(icg*3+j)*128+gc]
    f16* __restrict__ xg)                      // [T][B][8][128][8] f16
{
  const int b = blockIdx.x >> 3, row = blockIdx.x & 7;
  const int tc = blockIdx.y;                   // t-chunk: 8 steps
  const int tid = threadIdx.x;
  const int gc = tid >> 1, half = tid & 1;
  __shared__ float xs[8][256];
  __shared__ unsigned short wl[96*128];        // cx taps, 24 KB
  for (int i = tid; i < 96*128; i += 256) wl[i] = wcx16[i];
  const size_t dg = (size_t)b*2048 + row*256 + tid;
  #pragma unroll
  for (int tt = 0; tt < 8; ++tt){
    const size_t tb = (size_t)(tc*8 + tt)*BD + dg;
    xs[tt][tid] = (float)r0Hi[tb] + (float)r0Lo[tb];
  }
  __syncthreads();
  const int c0 = half*4;
  float acc0[8], acc1[8], acc2[8], acc3[8];
  #pragma unroll
  for (int tt = 0; tt < 8; ++tt){ acc0[tt]=0.f; acc1[tt]=0.f; acc2[tt]=0.f; acc3[tt]=0.f; }
  for (int ic2 = 0; ic2 < 32; ++ic2){
    const unsigned short* wq = &wl[ic2*3*128 + gc];
    const float wx0 = bf2f(wq[0]), wx1 = bf2f(wq[128]), wx2 = bf2f(wq[256]);
    #pragma unroll
    for (int tt = 0; tt < 8; ++tt){
      const float* xr = &xs[tt][ic2*8];
      {
        const int c = c0 + 0;
        float s = xr[c]*wx1;
        if (c > 0) s += xr[c-1]*wx0;
        s += xr[c+1]*wx2;
        acc0[tt] += s;
      }
      {
        const int c = c0 + 1;
        acc1[tt] += xr[c]*wx1 + xr[c-1]*wx0 + xr[c+1]*wx2;
      }
      {
        const int c = c0 + 2;
        acc2[tt] += xr[c]*wx1 + xr[c-1]*wx0 + xr[c+1]*wx2;
      }
      {
        const int c = c0 + 3;
        float s = xr[c]*wx1 + xr[c-1]*wx0;
        if (c < 7) s += xr[c+1]*wx2;
        acc3[tt] += s;
      }
    }
  }
  const size_t xgbase = ((size_t)b*8 + row)*1024 + gc*8 + half*4;
  #pragma unroll
  for (int tt = 0; tt < 8; ++tt){
    f16x4 o;
    o[0] = (f16)acc0[tt]; o[1] = (f16)acc1[tt];
    o[2] = (f16)acc2[tt]; o[3] = (f16)acc3[tt];
    *reinterpret_cast<f16x4*>(xg + (size_t)(tc*8 + tt)*XGT + xgbase) = o;
  }
}

// ---------------------------------------------------------------------------
// Layer-1 ConvLSTM for ALL 64 steps, h-conv only (x-conv precomputed in xg).
// ---------------------------------------------------------------------------
__global__ __launch_bounds__(256) void k_cell1_all(
    const f16* __restrict__ xg,                // [T][B][8][128][8]
    const float* __restrict__ h0s, const float* __restrict__ c0s,
    const unsigned short* __restrict__ wh16,   // [(icg*3+j)*128+gc]
    const float* __restrict__ cxb, const float* __restrict__ chb,
    f16* __restrict__ hrw1Hi)            // [T][B][2048]
{
  const int b = blockIdx.x >> 3, row = blockIdx.x & 7;
  const int tid = threadIdx.x;
  __shared__ float h_lds[264];
  __shared__ float P[128][2][9];
  __shared__ unsigned short wlds16[96*128];    // h taps only, 24 KB
  const int gc = tid >> 1, ih = tid & 1;
  for (int i = tid; i < 96*128; i += 256) wlds16[i] = wh16[i];
  const size_t dg = (size_t)b*2048 + row*256 + tid;
  const int ic = tid >> 3, col = tid & 7;
  const float bi = cxb[ic]    + chb[ic];
  const float bf = cxb[ic+32] + chb[ic+32];
  const float bo = cxb[ic+64] + chb[ic+64];
  const float bg = cxb[ic+96] + chb[ic+96];
  const int wofs = tid + ((tid >> 7) << 2);
  const int hbase = ih * 132;
  const size_t xgbase = ((size_t)b*8 + row)*1024 + gc*8;
  float c_reg = c0s[dg];
  h_lds[wofs] = h0s[dg];
  f16x8 xgv;
  if (ih == 0) xgv = *reinterpret_cast<const f16x8*>(xg + xgbase);
  __syncthreads();
  for (int t = 0; t < 64; ++t){
    f16x8 xgn;
    if (ih == 0 && t < 63)
      xgn = *reinterpret_cast<const f16x8*>(xg + (size_t)(t+1)*XGT + xgbase);
    {
      float g8[8];
      #pragma unroll
      for (int c2 = 0; c2 < 8; ++c2) g8[c2] = 0.f;
      #pragma unroll
      for (int icl = 0; icl < 16; ++icl){
        const int icg = ih*16 + icl;
        const float* hb = &h_lds[icl*8 + hbase];
        f32x4v hv0 = *reinterpret_cast<const f32x4v*>(hb);
        f32x4v hv1 = *reinterpret_cast<const f32x4v*>(hb + 4);
        const float hv[8] = {hv0[0],hv0[1],hv0[2],hv0[3],hv1[0],hv1[1],hv1[2],hv1[3]};
        const unsigned short* wq = &wlds16[icg*3*128 + gc];
        const float wh0 = bf2f(wq[0]);
        const float wh1 = bf2f(wq[128]);
        const float wh2 = bf2f(wq[256]);
        #pragma unroll
        for (int c2 = 0; c2 < 8; ++c2){
          float s = hv[c2]*wh1;
          if (c2 > 0) s += hv[c2-1]*wh0;
          if (c2 < 7) s += hv[c2+1]*wh2;
          g8[c2] += s;
        }
      }
      if (ih == 0){
        #pragma unroll
        for (int c2 = 0; c2 < 8; ++c2) g8[c2] += (float)xgv[c2];
      }
      #pragma unroll
      for (int c2 = 0; c2 < 8; ++c2) P[gc][ih][c2] = g8[c2];
    }
    __syncthreads();
    {
      const float ipre = P[ic   ][0][col] + P[ic   ][1][col] + bi;
      const float fpre = P[ic+32][0][col] + P[ic+32][1][col] + bf;
      const float opre = P[ic+64][0][col] + P[ic+64][1][col] + bo;
      const float gpre = P[ic+96][0][col] + P[ic+96][1][col] + bg;
      const float cn = sigmoidf_(fpre)*c_reg + sigmoidf_(ipre)*tanhf(gpre);
      c_reg = cn;
      const float hraw = sigmoidf_(opre)*tanhf(cn);
      hrw1Hi[(size_t)t*BD + dg] = (f16)hraw;
      __syncthreads();           // P reads done before next-iter overwrite
      h_lds[wofs] = hraw;
      if (ih == 0) xgv = xgn;
    }
  }
}

// ---------------------------------------------------------------------------
// MFMA inter-attention: block (b, t-half of 32). Writes ctx hi only.
// ---------------------------------------------------------------------------
__global__ __launch_bounds__(256) void k_attn(
    const f16* __restrict__ encF,    // [128][128][2048]
    const f16* __restrict__ encT,    // [128][2048][128]
    const f16* __restrict__ stHi,    // [T][B][2048]
    f16* __restrict__ ctxHi)         // [T][B][2048]
{
  const int b = blockIdx.x, th = blockIdx.y;
  const int tid = threadIdx.x, lane = tid & 63, wv = tid >> 6;
  __shared__ float S_lds[128][36];
  __shared__ float red[8][32];
  __shared__ float colv[32];
  __shared__ __align__(16) char aT[8192];
  const int kb = lane >> 5;
  // ---- phase 1
  {
    const int rA = wv*32 + (lane & 31);
    const int tcol = th*32 + (lane & 31);
    const f16* pA  = encF + ((size_t)b*128 + rA)*2048 + kb*8;
    const f16* pBH = stHi + ((size_t)tcol*128 + b)*2048 + kb*8;
    f32x16 acc;
    #pragma unroll
    for (int r = 0; r < 16; ++r) acc[r] = 0.f;
    #pragma unroll 4
    for (int s = 0; s < 128; ++s){
      f16x8 av = *reinterpret_cast<const f16x8*>(pA  + s*16);
      f16x8 bh = *reinterpret_cast<const f16x8*>(pBH + s*16);
      acc = __builtin_amdgcn_mfma_f32_32x32x16_f16(av, bh, acc, 0, 0, 0);
    }
    #pragma unroll
    for (int r = 0; r < 16; ++r){
      const int rr = 4*kb + (r & 3) + 8*(r >> 2);
      S_lds[wv*32 + rr][lane & 31] = acc[r];
    }
  }
  __syncthreads();
  // ---- phase 2: column softmax
  {
    const int c = tid & 31, g = tid >> 5;
    float ev[16];
    float m = -INFINITY;
    #pragma unroll
    for (int i = 0; i < 16; ++i){ ev[i] = S_lds[g*16 + i][c]; m = fmaxf(m, ev[i]); }
    red[g][c] = m;
    __syncthreads();
    if (tid < 32){
      float M = red[0][tid];
      #pragma unroll
      for (int j = 1; j < 8; ++j) M = fmaxf(M, red[j][tid]);
      colv[tid] = M;
    }
    __syncthreads();
    const float M = colv[c];
    float sum = 0.f;
    #pragma unroll
    for (int i = 0; i < 16; ++i){ ev[i] = __expf(ev[i] - M); sum += ev[i]; }
    __syncthreads();
    red[g][c] = sum;
    __syncthreads();
    if (tid < 32){
      float L = red[0][tid];
      #pragma unroll
      for (int j = 1; j < 8; ++j) L += red[j][tid];
      colv[tid] = 1.f / L;
    }
    __syncthreads();
    const float inv = colv[c];
    f16x8 w0, w1;
    #pragma unroll
    for (int j = 0; j < 8; ++j){
      w0[j] = (f16)(ev[j] * inv);
      w1[j] = (f16)(ev[8 + j] * inv);
    }
    const int sw = (c & 15) << 4;
    *reinterpret_cast<f16x8*>(aT + c*256 + (((g*2    )*16) ^ sw)) = w0;
    *reinterpret_cast<f16x8*>(aT + c*256 + (((g*2 + 1)*16) ^ sw)) = w1;
  }
  __syncthreads();
  // ---- phase 3
  {
    const int arow = lane & 31;
    const int asw = (arow & 15) << 4;
    f16x8 afr[8];
    #pragma unroll
    for (int ks = 0; ks < 8; ++ks){
      const int chunk = 2*ks + kb;
      afr[ks] = *reinterpret_cast<const f16x8*>(aT + arow*256 + ((chunk*16) ^ asw));
    }
    for (int nt = wv; nt < 64; nt += 4){
      const int d = nt*32 + (lane & 31);
      const f16* pB = encT + ((size_t)b*2048 + d)*128 + kb*8;
      f32x16 acc;
      #pragma unroll
      for (int r = 0; r < 16; ++r) acc[r] = 0.f;
      #pragma unroll
      for (int ks = 0; ks < 8; ++ks){
        f16x8 bv = *reinterpret_cast<const f16x8*>(pB + ks*16);
        acc = __builtin_amdgcn_mfma_f32_32x32x16_f16(afr[ks], bv, acc, 0, 0, 0);
      }
      #pragma unroll
      for (int r = 0; r < 16; ++r){
        const int rr = 4*kb + (r & 3) + 8*(r >> 2);
        const size_t o = ((size_t)(th*32 + rr)*128 + b)*2048 + d;
        ctxHi[o] = (f16)acc[r];
      }
    }
  }
}

// ---------------------------------------------------------------------------
// Batched full-K ia GEMM (all t): p[t] = tanh([A0|A1]@W + bias), f16 hi/lo.
// ---------------------------------------------------------------------------
__global__ __launch_bounds__(256, 2) void k_gemm_full(
    const f16* __restrict__ a0, const f16* __restrict__ a1,
    const f16* __restrict__ wHp, const float* __restrict__ bias,
    f16* __restrict__ outHi, f16* __restrict__ outLo)
{
  const int nt = blockIdx.x, t = blockIdx.y;
  const size_t tb = (size_t)t * BD;
  const int tid = threadIdx.x;
  const int lane = tid & 63, wv = tid >> 6;
  __shared__ __align__(16) char lds[49152];
  const f16* wH = wHp + (size_t)(nt*64)*4096;

  auto stage = [&](int buf, int ki){
    char* lb = lds + buf*24576;
    const f16* aH = ((ki < 32) ? a0 : a1) + tb;
    const int ke = (ki & 31) * 64;
    #pragma unroll
    for (int i = 0; i < 4; ++i){
      const int c = i*256 + tid, row = c >> 3;
      const int srcb = ((c & 7)*16) ^ ((row & 7) << 4);
      g2l16((const char*)(aH + (size_t)row*2048 + ke) + srcb, lb + c*16);
    }
    #pragma unroll
    for (int i = 0; i < 2; ++i){
      const int c = i*256 + tid, row = c >> 3;
      const int srcb = ((c & 7)*16) ^ ((row & 7) << 4);
      g2l16((const char*)(wH + (size_t)row*4096 + ki*64) + srcb, lb + 16384 + c*16);
    }
  };

  f32x16 acc0, acc1;
  #pragma unroll
  for (int r = 0; r < 16; ++r){ acc0[r] = 0.f; acc1[r] = 0.f; }
  const int rA = wv*32 + (lane & 31);
  const int kb = lane >> 5;
  const int rB0 = lane & 31;
  const int aswz = (rA & 7) << 4;
  const int bswz = (rB0 & 7) << 4;

  stage(0, 0);
  __syncthreads();
  for (int ki = 0; ki < 64; ++ki){
    const int buf = ki & 1;
    if (ki < 63) stage(buf ^ 1, ki + 1);
    const char* lb = lds + buf*24576;
    #pragma unroll
    for (int s = 0; s < 4; ++s){
      const int cb = s*32 + kb*16;
      f16x8 ah  = *reinterpret_cast<const f16x8*>(lb + rA*128 + (cb ^ aswz));
      f16x8 b0h = *reinterpret_cast<const f16x8*>(lb + 16384 + rB0*128 + (cb ^ bswz));
      f16x8 b1h = *reinterpret_cast<const f16x8*>(lb + 16384 + 4096 + rB0*128 + (cb ^ bswz));
      acc0 = __builtin_amdgcn_mfma_f32_32x32x16_f16(ah, b0h, acc0, 0, 0, 0);
      acc1 = __builtin_amdgcn_mfma_f32_32x32x16_f16(ah, b1h, acc1, 0, 0, 0);
    }
    __syncthreads();
  }

  const int col0 = nt*64 + (lane & 31);
  const float b0 = bias[col0], b1 = bias[col0 + 32];
  const int rowBase = wv*32 + 4*kb;
  #pragma unroll
  for (int r = 0; r < 16; ++r){
    const int rr = rowBase + (r & 3) + 8*(r >> 2);
    const size_t o = tb + (size_t)rr*2048 + col0;
    const float p = tanhf(acc0[r] + b0);
    const float q = tanhf(acc1[r] + b1);
    const f16 ph = (f16)p, qh = (f16)q;
    outHi[o]      = ph;  outLo[o]      = (f16)(p - (float)ph);
    outHi[o + 32] = qh;  outLo[o + 32] = (f16)(q - (float)qh);
  }
}

// ---------------------------------------------------------------------------
// Batched sa GEMM (all t): A = p hi (single pass), W = [Wlow^T|Wup^T].
// nt<32 -> Y (f32, raw); nt>=32 -> G (f16). Grid (64 nt, 64 t), K=2048.
// ---------------------------------------------------------------------------
__global__ __launch_bounds__(256, 2) void k_gemm_full2(
    const f16* __restrict__ aHi,                                // [T][B][2048]
    const f16* __restrict__ wSp,                                // [4096][2048]
    float* __restrict__ Y, f16* __restrict__ G)                 // [T][B][2048]
{
  const int nt = blockIdx.x, t = blockIdx.y;
  const size_t tb = (size_t)t * BD;
  const int tid = threadIdx.x;
  const int lane = tid & 63, wv = tid >> 6;
  __shared__ __align__(16) char lds[49152];
  const f16* wH = wSp + (size_t)(nt*64)*2048;
  const f16* aH = aHi + tb;

  auto stage = [&](int buf, int ki){
    char* lb = lds + buf*24576;
    const int ke = ki*64;
    #pragma unroll
    for (int i = 0; i < 4; ++i){
      const int c = i*256 + tid, row = c >> 3;
      const int srcb = ((c & 7)*16) ^ ((row & 7) << 4);
      g2l16((const char*)(aH + (size_t)row*2048 + ke) + srcb, lb + c*16);
    }
    #pragma unroll
    for (int i = 0; i < 2; ++i){
      const int c = i*256 + tid, row = c >> 3;
      const int srcb = ((c & 7)*16) ^ ((row & 7) << 4);
      g2l16((const char*)(wH + (size_t)row*2048 + ke) + srcb, lb + 16384 + c*16);
    }
  };

  f32x16 acc0, acc1;
  #pragma unroll
  for (int r = 0; r < 16; ++r){ acc0[r] = 0.f; acc1[r] = 0.f; }
  const int rA = wv*32 + (lane & 31);
  const int kb = lane >> 5;
  const int rB0 = lane & 31;
  const int aswz = (rA & 7) << 4;
  const int bswz = (rB0 & 7) << 4;

  stage(0, 0);
  __syncthreads();
  for (int ki = 0; ki < 32; ++ki){
    const int buf = ki & 1;
    if (ki < 31) stage(buf ^ 1, ki + 1);
    const char* lb = lds + buf*24576;
    #pragma unroll
    for (int s = 0; s < 4; ++s){
      const int cb = s*32 + kb*16;
      f16x8 ah  = *reinterpret_cast<const f16x8*>(lb + rA*128 + (cb ^ aswz));
      f16x8 b0h = *reinterpret_cast<const f16x8*>(lb + 16384 + rB0*128 + (cb ^ bswz));
      f16x8 b1h = *reinterpret_cast<const f16x8*>(lb + 16384 + 4096 + rB0*128 + (cb ^ bswz));
      acc0 = __builtin_amdgcn_mfma_f32_32x32x16_f16(ah, b0h, acc0, 0, 0, 0);
      acc1 = __builtin_amdgcn_mfma_f32_32x32x16_f16(ah, b1h, acc1, 0, 0, 0);
    }
    __syncthreads();
  }

  const int col0 = nt*64 + (lane & 31);
  const int rowBase = wv*32 + 4*kb;
  if (nt < 32){
    float* yp = Y + tb + col0;
    #pragma unroll
    for (int r = 0; r < 16; ++r){
      const int rr = rowBase + (r & 3) + 8*(r >> 2);
      yp[(size_t)rr*2048]      = acc0[r];
      yp[(size_t)rr*2048 + 32] = acc1[r];
    }
  } else {
    f16* gp = G + tb + (col0 - 2048);
    #pragma unroll
    for (int r = 0; r < 16; ++r){
      const int rr = rowBase + (r & 3) + 8*(r >> 2);
      gp[(size_t)rr*2048]      = (f16)acc0[r];
      gp[(size_t)rr*2048 + 32] = (f16)acc1[r];
    }
  }
}

// ---------------------------------------------------------------------------
// Chunk score kernel: S[i][t'] = (rHi+rLo)[i] . (pHi+pLo)[t'] for i in
// [i0+8*ih, i0+8*ih+8), t' in [i0+16, 64). Block (b, ih); 8 r-rows cached in
// LDS f32 (padded, conflict-free). Writes Smat[b][t'][i] f32.
// ---------------------------------------------------------------------------
__global__ __launch_bounds__(512) void k_scores(
    const f16* __restrict__ rHi, const f16* __restrict__ rLo,   // [T][B][2048]
    const f16* __restrict__ pHi, const f16* __restrict__ pLo,   // [T][B][2048]
    float* __restrict__ Smat,                                   // [B][64][64]
    const int i0)
{
  const int b = blockIdx.x, ih = blockIdx.y;
  const int tid = threadIdx.x, lane = tid & 63, wv = tid >> 6;  // 8 waves
  const int ibase = i0 + 8*ih;
  __shared__ float rs[8*2112];   // 8 rows, padded stride (d + (d>>5))
  // cooperative load: thread -> (row = tid>>6, d0 = lane*32)
  {
    const int row = tid >> 6;
    const int d0 = lane * 32;
    const f16* rh = rHi + ((size_t)(ibase + row)*128 + b)*2048 + d0;
    const f16* rl = rLo + ((size_t)(ibase + row)*128 + b)*2048 + d0;
    #pragma unroll
    for (int q = 0; q < 4; ++q){
      f16x8 h8 = *reinterpret_cast<const f16x8*>(rh + q*8);
      f16x8 l8 = *reinterpret_cast<const f16x8*>(rl + q*8);
      #pragma unroll
      for (int j = 0; j < 8; ++j){
        const int d = d0 + q*8 + j;
        rs[row*2112 + d + (d >> 5)] = (float)h8[j] + (float)l8[j];
      }
    }
  }
  __syncthreads();
  // each wave handles t' strided by 8
  for (int tp = i0 + 16 + wv; tp < 64; tp += 8){
    const int d0 = lane * 32;
    const f16* ph = pHi + ((size_t)tp*128 + b)*2048 + d0;
    const f16* pl = pLo + ((size_t)tp*128 + b)*2048 + d0;
    float pv[32];
    #pragma unroll
    for (int q = 0; q < 4; ++q){
      f16x8 h8 = *reinterpret_cast<const f16x8*>(ph + q*8);
      f16x8 l8 = *reinterpret_cast<const f16x8*>(pl + q*8);
      #pragma unroll
      for (int j = 0; j < 8; ++j) pv[q*8+j] = (float)h8[j] + (float)l8[j];
    }
    float dots[8];
    #pragma unroll
    for (int i = 0; i < 8; ++i){
      const float* rr = &rs[i*2112 + lane*33];
      float acc = 0.f;
      #pragma unroll
      for (int j = 0; j < 32; ++j) acc += rr[j] * pv[j];
      dots[i] = acc;
    }
    #pragma unroll
    for (int i = 0; i < 8; ++i){
      float v = dots[i];
      #pragma unroll
      for (int off = 1; off < 64; off <<= 1) v += __shfl_xor(v, off);
      dots[i] = v;
    }
    if (lane == 0){
      float* so = Smat + ((size_t)b*64 + tp)*64 + ibase;
      #pragma unroll
      for (int i = 0; i < 8; ++i) so[i] = dots[i];
    }
  }
}

// ---------------------------------------------------------------------------
// Self-attention refine chain, chunked: t in [t0, t0+16). Old scores (i<t0)
// read from Smat; intra-chunk dots (<=15) computed serially. Block per b,
// 1024 threads.
// ---------------------------------------------------------------------------
__global__ __launch_bounds__(1024) void k_selfchain_c(
    const f16* __restrict__ pHi, const f16* __restrict__ pLo,   // [T][B][2048]
    const float* __restrict__ Y, const f16* __restrict__ G,     // [T][B][2048]
    const float* __restrict__ bias,
    f16* __restrict__ rHi, f16* __restrict__ rLo,               // [T][B][2048]
    const float* __restrict__ Smat,                             // [B][64][64]
    const int t0)
{
  const int b = blockIdx.x;
  const int tid = threadIdx.x, lane = tid & 63, wv = tid >> 6;   // 16 waves
  __shared__ float sc[64];
  __shared__ float a_lds[64];
  const int d0 = tid * 2;
  f32x2v bb = *reinterpret_cast<const f32x2v*>(bias + d0);
  for (int t = t0; t < t0 + 16; ++t){
    const size_t pb = ((size_t)t*128 + b)*2048;
    if (t > 0){
      // old scores from Smat
      if (tid < t0) sc[tid] = Smat[((size_t)b*64 + t)*64 + tid];
      // intra-chunk dots: i in [t0, t), wave wv handles i = t0 + wv
      if (wv < t - t0){
        float hreg[32];
        #pragma unroll
        for (int jj = 0; jj < 4; ++jj){
          const int d = (jj*64 + lane)*8;
          f16x8 h8 = *reinterpret_cast<const f16x8*>(pHi + pb + d);
          f16x8 l8 = *reinterpret_cast<const f16x8*>(pLo + pb + d);
          #pragma unroll
          for (int j = 0; j < 8; ++j) hreg[jj*8+j] = (float)h8[j] + (float)l8[j];
        }
        const int i = t0 + wv;
        const f16* rh = rHi + ((size_t)i*128 + b)*2048;
        const f16* rl = rLo + ((size_t)i*128 + b)*2048;
        float dot = 0.f;
        #pragma unroll
        for (int jj = 0; jj < 4; ++jj){
          const int d = (jj*64 + lane)*8;
          f16x8 h8 = *reinterpret_cast<const f16x8*>(rh + d);
          f16x8 l8 = *reinterpret_cast<const f16x8*>(rl + d);
          #pragma unroll
          for (int j = 0; j < 8; ++j)
            dot += ((float)h8[j] + (float)l8[j]) * hreg[jj*8+j];
        }
        #pragma unroll
        for (int off = 1; off < 64; off <<= 1) dot += __shfl_xor(dot, off);
        if (lane == 0) sc[i] = dot;
      }
      __syncthreads();
      if (tid < 64){
        const float s = (tid < t) ? sc[tid] : -INFINITY;
        float mm = s;
        #pragma unroll
        for (int off = 1; off < 64; off <<= 1) mm = fmaxf(mm, __shfl_xor(mm, off));
        const float e = (tid < t) ? __expf(s - mm) : 0.f;
        float sum = e;
        #pragma unroll
        for (int off = 1; off < 64; off <<= 1) sum += __shfl_xor(sum, off);
        a_lds[tid] = e / sum;
      }
      __syncthreads();
    }
    float y0, y1;
    {
      f32x2v yv = *reinterpret_cast<const f32x2v*>(Y + (size_t)t*BD + (size_t)b*2048 + d0);
      y0 = yv[0] + bb[0];
      y1 = yv[1] + bb[1];
    }
    if (t > 0){
      float z0 = 0.f, z1 = 0.f;
      int i = 0;
      for (; i + 1 < t; i += 2){
        const float a0 = a_lds[i], a1 = a_lds[i+1];
        f16x2 g0 = *reinterpret_cast<const f16x2*>(G + ((size_t)i*128 + b)*2048 + d0);
        f16x2 g1 = *reinterpret_cast<const f16x2*>(G + ((size_t)(i+1)*128 + b)*2048 + d0);
        y0 += a0 * (float)g0[0];
        y1 += a0 * (float)g0[1];
        z0 += a1 * (float)g1[0];
        z1 += a1 * (float)g1[1];
      }
      if (i < t){
        const float a0 = a_lds[i];
        f16x2 g0 = *reinterpret_cast<const f16x2*>(G + ((size_t)i*128 + b)*2048 + d0);
        y0 += a0 * (float)g0[0];
        y1 += a0 * (float)g0[1];
      }
      y0 += z0;
      y1 += z1;
    }
    f16x2 hh, ll;
    {
      const float v0 = tanhf(y0);
      const float v1 = tanhf(y1);
      hh[0] = (f16)v0; ll[0] = (f16)(v0 - (float)hh[0]);
      hh[1] = (f16)v1; ll[1] = (f16)(v1 - (float)hh[1]);
    }
    *reinterpret_cast<f16x2*>(rHi + pb + d0) = hh;
    *reinterpret_cast<f16x2*>(rLo + pb + d0) = ll;
    __syncthreads();   // r[t] stores drained before t+1 intra dots read them
  }
}

// ---------------------------------------------------------------------------
// Head stage 1: z1 = relu(r1(8192x2048) @ hw1 + hb1), single-pass f16 MFMA
// ---------------------------------------------------------------------------
__global__ __launch_bounds__(256) void k_headgemm(
    const f16* __restrict__ aHi,
    const f16* __restrict__ w1H,   // [224][2048]
    const float* __restrict__ hb1,
    float* __restrict__ z1)        // [8192][224]
{
  const int mb = blockIdx.x;
  const int nt = blockIdx.y;
  const int lane = threadIdx.x & 63, wv = threadIdx.x >> 6;
  const int rowA = mb*128 + wv*32 + (lane & 31);
  const int kb = lane >> 5;
  const int n = nt*32 + (lane & 31);
  const f16* pAH = aHi + (size_t)rowA*2048 + kb*8;
  const f16* pBH = w1H + (size_t)n*2048 + kb*8;
  f32x16 acc;
  #pragma unroll
  for (int r = 0; r < 16; ++r) acc[r] = 0.f;
  #pragma unroll 4
  for (int s = 0; s < 128; ++s){
    f16x8 ah = *reinterpret_cast<const f16x8*>(pAH + s*16);
    f16x8 bh = *reinterpret_cast<const f16x8*>(pBH + s*16);
    acc = __builtin_amdgcn_mfma_f32_32x32x16_f16(ah, bh, acc, 0, 0, 0);
  }
  const float bias = (n < 200) ? hb1[n] : 0.f;
  const int rowBase = mb*128 + wv*32 + 4*kb;
  #pragma unroll
  for (int r = 0; r < 16; ++r){
    const int rr = rowBase + (r & 3) + 8*(r >> 2);
    z1[(size_t)rr*224 + n] = fmaxf(acc[r] + bias, 0.f);
  }
}

// Head stage 2
__global__ __launch_bounds__(256) void k_head2(
    const float* __restrict__ z1,
    const float* __restrict__ hw2, const float* __restrict__ hb2,
    const float* __restrict__ hw3, const float* __restrict__ hb3,
    float* __restrict__ out)
{
  const int r0 = blockIdx.x * 64;
  const int tid = threadIdx.x;
  __shared__ float zl[64][200];
  __shared__ float z2[64][50];
  for (int i = tid; i < 64*200; i += 256){
    const int r = i / 200, n = i % 200;
    zl[r][n] = z1[(size_t)(r0 + r)*224 + n];
  }
  __syncthreads();
  for (int i = tid; i < 64*50; i += 256){
    const int r = i / 50, n = i % 50;
    float s = hb2[n];
    for (int k = 0; k < 200; ++k) s += zl[r][k] * hw2[k*50 + n];
    z2[r][n] = fmaxf(s, 0.f);
  }
  __syncthreads();
  for (int i = tid; i < 128; i += 256){
    const int r = i >> 1, c = i & 1;
    float s = hb3[c];
    for (int k = 0; k < 50; ++k) s += z2[r][k] * hw3[k*2 + c];
    const int rg = r0 + r;
    const int tt = rg >> 7, b = rg & 127;
    out[(size_t)b*128 + tt*2 + c] = s;
  }
}

// ---------------------------------------------------------------------------
extern "C" void kernel_launch(void* const* d_in, const int* in_sizes, int n_in,
                              void* d_out, int out_size, void* d_ws, size_t ws_size,
                              hipStream_t stream)
{
  (void)in_sizes; (void)n_in; (void)out_size; (void)ws_size;
  const float* x_flat = (const float*)d_in[0];
  const float* enc    = (const float*)d_in[1];
  const float* h0     = (const float*)d_in[2];
  const float* c0     = (const float*)d_in[3];
  const float* cx_w0  = (const float*)d_in[4];
  const float* cx_b0  = (const float*)d_in[5];
  const float* ch_w0  = (const float*)d_in[6];
  const float* ch_b0  = (const float*)d_in[7];
  const float* cx_w1  = (const float*)d_in[8];
  const float* cx_b1  = (const float*)d_in[9];
  const float* ch_w1  = (const float*)d_in[10];
  const float* ch_b1  = (const float*)d_in[11];
  const float* ia_w0  = (const float*)d_in[12];
  const float* ia_b0  = (const float*)d_in[13];
  const float* sa_w0  = (const float*)d_in[14];
  const float* sa_b0  = (const float*)d_in[15];
  const float* ia_w1  = (const float*)d_in[16];
  const float* ia_b1  = (const float*)d_in[17];
  const float* sa_w1  = (const float*)d_in[18];
  const float* sa_b1  = (const float*)d_in[19];
  const float* hw1    = (const float*)d_in[20];
  const float* hb1    = (const float*)d_in[21];
  const float* hw2    = (const float*)d_in[22];
  const float* hb2    = (const float*)d_in[23];
  const float* hw3    = (const float*)d_in[24];
  const float* hb3    = (const float*)d_in[25];
  float* out = (float*)d_out;

  char* ws = (char*)d_ws;
  size_t off = 0;
  auto alloc = [&](size_t bytes) -> char* {
    char* p = ws + off;
    off += (bytes + 255) & ~(size_t)255;
    return p;
  };
  const size_t WPLANE = (size_t)2048*4096*2;   // 16 MiB
  const size_t TPLANE = (size_t)64*BD*2;       // 32 MiB, [T][B][D] f16
  f16* wIa0 = (f16*)alloc(WPLANE);
  f16* wSa0 = (f16*)alloc(WPLANE);   // [4096][2048]: Wlow^T rows 0..2047, Wup^T rows 2048..
  f16* wIa1 = (f16*)alloc(WPLANE);
  f16* wSa1 = (f16*)alloc(WPLANE);
  f16* w1H  = (f16*)alloc((size_t)224*2048*2);
  f16* encF = (f16*)alloc((size_t)128*128*2048*2);   // 64 MiB
  f16* encT = (f16*)alloc((size_t)128*2048*128*2);   // 64 MiB
  f16* S1 = (f16*)alloc(TPLANE);
  f16* S2 = (f16*)alloc(TPLANE);
  f16* S3 = (f16*)alloc(TPLANE);
  f16* S4 = (f16*)alloc(TPLANE);
  f16* S5 = (f16*)alloc(TPLANE);
  f16* S6 = (f16*)alloc(TPLANE);
  f16* S7 = (f16*)alloc(TPLANE);
  f16* S8 = (f16*)alloc(TPLANE);
  unsigned short* wh16  = (unsigned short*)alloc((size_t)96*128*2);
  unsigned short* wcx16 = (unsigned short*)alloc((size_t)96*128*2);
  float* Smat = (float*)alloc((size_t)128*64*64*4);   // 2 MiB score matrix
  // total ws ~= 451 MiB. Alias names (lifetimes verified disjoint):
  f16*  hr0AHi = S1;                         // layer-0 raw h (hi only)
  f16*  ctx0Hi = S3;
  f16*  p0Hi   = S5;  f16* p0Lo   = S6;
  float* Y0 = (float*)S1;                    // 64 MiB over S1+S2 (contiguous)
  f16*  G0  = S3;
  f16*  r0Hi = S7;    f16* r0Lo   = S8;
  f16*  xgb  = S1;                           // 128 MiB over S1..S4 (contiguous);
                                             // live [k_xconv, k_cell1_all] only
  f16*  hrw1Hi = S5;                         // hi only
  f16*  ctx1Hi = S1;
  f16*  p1Hi = S7;    f16* p1Lo   = S8;
  float* Y1 = (float*)S1;                    // 64 MiB over S1+S2
  f16*  G1  = S4;
  f16*  r1Hi = S5;    f16* r1Lo   = S3;
  float* z1 = (float*)wSa0;                  // head scratch (wSa0 dead by then)

  // ---- prologue -----------------------------------------------------------
  k_transpose_f16<<<dim3(64,128),256,0,stream>>>(ia_w0, wIa0, 4096, 2048);
  k_transpose_f16<<<dim3(64,128),256,0,stream>>>(ia_w1, wIa1, 4096, 2048);
  k_transpose_f16<<<dim3(64,64),256,0,stream>>>(sa_w0, wSa0, 2048, 2048);
  k_transpose_f16<<<dim3(64,64),256,0,stream>>>(sa_w0 + (size_t)2048*2048,
                                                wSa0 + (size_t)2048*2048, 2048, 2048);
  k_transpose_f16<<<dim3(64,64),256,0,stream>>>(sa_w1, wSa1, 2048, 2048);
  k_transpose_f16<<<dim3(64,64),256,0,stream>>>(sa_w1 + (size_t)2048*2048,
                                                wSa1 + (size_t)2048*2048, 2048, 2048);
  k_transpose_f16<<<dim3(7,64),256,0,stream>>>(hw1, w1H, 2048, 200);
  k_enc_prep<<<dim3(64,4,128),256,0,stream>>>(enc, encF, encT);
  k_pack_cellw<<<16,256,0,stream>>>(ch_w1, cx_w1, wh16, wcx16);

  // ---- layer 0 (fully batched + chunked self-attn chain) ------------------
  k_cell0<<<1024,256,0,stream>>>(x_flat, h0, c0, cx_w0, cx_b0, ch_w0, ch_b0,
                                 hr0AHi);
  k_attn<<<dim3(128,2),256,0,stream>>>(encF, encT, hr0AHi, ctx0Hi);
  k_gemm_full<<<dim3(32,64),256,0,stream>>>(hr0AHi, ctx0Hi,
                                            wIa0, ia_b0, p0Hi, p0Lo);
  k_gemm_full2<<<dim3(64,64),256,0,stream>>>(p0Hi, wSa0, Y0, G0);
  for (int c = 0; c < 4; ++c){
    k_selfchain_c<<<128,1024,0,stream>>>(p0Hi, p0Lo, Y0, G0, sa_b0,
                                         r0Hi, r0Lo, Smat, c*16);
    if (c < 3)
      k_scores<<<dim3(128,2),512,0,stream>>>(r0Hi, r0Lo, p0Hi, p0Lo, Smat, c*16);
  }

  // ---- layer 1: grid-parallel x-conv, persistent h-cell, batched rest -----
  k_xconv<<<dim3(1024,8),256,0,stream>>>(r0Hi, r0Lo, wcx16, xgb);
  k_cell1_all<<<1024,256,0,stream>>>(xgb,
                                     h0 + (size_t)128*2048, c0 + (size_t)128*2048,
                                     wh16, cx_b1, ch_b1, hrw1Hi);
  k_attn<<<dim3(128,2),256,0,stream>>>(encF, encT, hrw1Hi, ctx1Hi);
  k_gemm_full<<<dim3(32,64),256,0,stream>>>(hrw1Hi, ctx1Hi,
                                            wIa1, ia_b1, p1Hi, p1Lo);
  k_gemm_full2<<<dim3(64,64),256,0,stream>>>(p1Hi, wSa1, Y1, G1);
  for (int c = 0; c < 4; ++c){
    k_selfchain_c<<<128,1024,0,stream>>>(p1Hi, p1Lo, Y1, G1, sa_b1,
                                         r1Hi, r1Lo, Smat, c*16);
    if (c < 3)
      k_scores<<<dim3(128,2),512,0,stream>>>(r1Hi, r1Lo, p1Hi, p1Lo, Smat, c*16);
  }

  // ---- head (batched over all t,b) ----------------------------------------
  k_headgemm<<<dim3(64,7),256,0,stream>>>(r1Hi, w1H, hb1, z1);
  k_head2<<<128,256,0,stream>>>(z1, hw2, hb2, hw3, hb3, out);
}

// Round 18
// 3436.864 us; speedup vs baseline: 1.1101x; 1.1101x over previous
//
#include <hip/hip_runtime.h>
#include <math.h>

// ---------------------------------------------------------------------------
// CLSADecoder: 2-layer RowSharedConvLSTM + inter-attn + causal self-attn + head
// B=128, T=64, D=2048 (ROWS=8, CH=32, COLS=8), S=128.
// R17: revert R16's selfchain chunking (regressed: 8 serialized chunk
// launches + 6 score kernels cost more than the score-traffic they saved).
// Back to R15's single-kernel 1024-thread selfchain. New: k_cell0 weight
// registers (48 f32 -> VGPR 192 -> 2 blocks/CU) moved to a 24KB f16 LDS
// table like cell1's (VGPR ~150 -> 3 blocks/CU), mirroring the 586 vs 438us
// gap between the two cell kernels.
// ---------------------------------------------------------------------------

typedef _Float16 f16;
typedef _Float16 f16x8 __attribute__((ext_vector_type(8)));
typedef _Float16 f16x4 __attribute__((ext_vector_type(4)));
typedef _Float16 f16x2 __attribute__((ext_vector_type(2)));
typedef float  f32x16 __attribute__((ext_vector_type(16)));
typedef float  f32x4v __attribute__((ext_vector_type(4)));
typedef float  f32x2v __attribute__((ext_vector_type(2)));
typedef unsigned short u16x8 __attribute__((ext_vector_type(8)));
typedef unsigned short u16x4 __attribute__((ext_vector_type(4)));

#define BD 262144   // 128*2048  (one [B][D] plane)
#define XGT 1048576 // xg per-t stride: 128*8*1024 elements

__device__ __forceinline__ unsigned short f2bf(float x){
  unsigned int u = __builtin_bit_cast(unsigned int, x);
  u += 0x7fffu + ((u >> 16) & 1u);
  return (unsigned short)(u >> 16);
}
__device__ __forceinline__ float bf2f(unsigned short h){
  unsigned int u = ((unsigned int)h) << 16;
  return __builtin_bit_cast(float, u);
}
__device__ __forceinline__ float sigmoidf_(float x){
  return 1.0f / (1.0f + __expf(-x));
}
__device__ __forceinline__ void g2l16(const void* g, void* l){
  __builtin_amdgcn_global_load_lds(
      (const __attribute__((address_space(1))) unsigned int*)g,
      (__attribute__((address_space(3))) unsigned int*)l,
      16, 0, 0);
}

// ---------------------------------------------------------------------------
// transpose f32 weight [K][N] -> f16 plane [N][K]
// ---------------------------------------------------------------------------
__global__ __launch_bounds__(256) void k_transpose_f16(
    const float* __restrict__ src, f16* __restrict__ dhi,
    const int K, const int N)
{
  __shared__ float tile[32][33];
  const int n0 = blockIdx.x * 32, k0 = blockIdx.y * 32;
  const int tx = threadIdx.x & 31, ty = threadIdx.x >> 5;
  #pragma unroll
  for (int ii = 0; ii < 4; ++ii){
    const int k = k0 + ty + ii*8, n = n0 + tx;
    float v = (n < N) ? src[(size_t)k * N + n] : 0.0f;
    tile[ty + ii*8][tx] = v;
  }
  __syncthreads();
  #pragma unroll
  for (int ii = 0; ii < 4; ++ii){
    const int n = n0 + ty + ii*8, k = k0 + tx;
    dhi[(size_t)n * K + k] = (f16)tile[tx][ty + ii*8];
  }
}

// enc f32 -> encF (f16, [b][s][d]) and encT (f16, [b][d][s])
__global__ __launch_bounds__(256) void k_enc_prep(
    const float* __restrict__ enc,
    f16* __restrict__ encF, f16* __restrict__ encT)
{
  __shared__ float tile[32][33];
  const int dt = blockIdx.x;   // 0..63
  const int st = blockIdx.y;   // 0..3
  const int b  = blockIdx.z;   // 0..127
  const int tx = threadIdx.x & 31, ty = threadIdx.x >> 5;
  const int d0 = dt*32, s0 = st*32;
  #pragma unroll
  for (int ii = 0; ii < 4; ++ii){
    const int s = s0 + ty + ii*8, d = d0 + tx;
    const float v = enc[((size_t)b*128 + s)*2048 + d];
    tile[ty + ii*8][tx] = v;
    encF[((size_t)b*128 + s)*2048 + d] = (f16)v;
  }
  __syncthreads();
  #pragma unroll
  for (int ii = 0; ii < 4; ++ii){
    const int d = d0 + ty + ii*8, s = s0 + tx;
    encT[((size_t)b*2048 + d)*128 + s] = (f16)tile[tx][ty + ii*8];
  }
}

// split cell1 conv weights: wh16[(icg*3+j)*128+gc] (h taps),
// wcx16[(icg*3+j)*128+gc] (x taps), bf16.
__global__ void k_pack_cellw(const float* __restrict__ chw,
                             const float* __restrict__ cxw,
                             unsigned short* __restrict__ wh16,
                             unsigned short* __restrict__ wcx16)
{
  const int i = blockIdx.x * 256 + threadIdx.x;   // i = gc*32 + icg
  if (i < 128 * 32){
    const int gc = i >> 5, icg = i & 31;
    #pragma unroll
    for (int k = 0; k < 3; ++k){
      wh16[(icg*3 + k)*128 + gc]  = f2bf(chw[i*3 + k]);
      wcx16[(icg*3 + k)*128 + gc] = f2bf(cxw[i*3 + k]);
    }
  }
}

// cell0 h-taps -> f16 table w0h16[(icg*3+j)*128+gc]
__global__ void k_pack_cellw0(const float* __restrict__ chw,
                              f16* __restrict__ w0h16)
{
  const int i = blockIdx.x * 256 + threadIdx.x;   // i = gc*32 + icg
  if (i < 128 * 32){
    const int gc = i >> 5, icg = i & 31;
    #pragma unroll
    for (int k = 0; k < 3; ++k)
      w0h16[(icg*3 + k)*128 + gc] = (f16)chw[i*3 + k];
  }
}

// ---------------------------------------------------------------------------
// Layer-0 ConvLSTM for ALL 64 steps. Block=(b,row). Writes hraw hi only.
// h-taps in 24KB f16 LDS table (VGPR relief: 192 -> ~150).
// ---------------------------------------------------------------------------
__global__ __launch_bounds__(256) void k_cell0(
    const float* __restrict__ x_flat,
    const float* __restrict__ h0, const float* __restrict__ c0,
    const float* __restrict__ cxw, const float* __restrict__ cxb,
    const f16* __restrict__ w0h16, const float* __restrict__ chb,
    f16* __restrict__ hrawHi)     // [T][B][2048]
{
  const int b = blockIdx.x >> 3, row = blockIdx.x & 7;
  const int tid = threadIdx.x;
  __shared__ float h_lds[264];
  __shared__ float x_lds[8];
  __shared__ float P[128][2][9];
  __shared__ f16 wlds[96*128];                 // h taps, 24 KB
  const int gc = tid >> 1, ih = tid & 1;
  for (int i = tid; i < 96*128; i += 256) wlds[i] = w0h16[i];
  const float wx0 = cxw[gc*3+0], wx1 = cxw[gc*3+1], wx2 = cxw[gc*3+2];
  const float bsum = cxb[gc] + chb[gc];
  const int ic = tid >> 3, col = tid & 7;
  const size_t dg = (size_t)b*2048 + row*256 + tid;
  const int wofs = tid + ((tid >> 7) << 2);
  const int hbase = ih * 132;
  float c_reg = c0[dg];
  h_lds[wofs] = h0[dg];
  float xnext = (tid < 8) ? x_flat[((size_t)b*64 + 0)*64 + row*8 + tid] : 0.f;
  __syncthreads();
  for (int t = 0; t < 64; ++t){
    if (tid < 8) x_lds[tid] = xnext;
    __syncthreads();
    if (t < 63 && tid < 8)
      xnext = x_flat[((size_t)b*64 + t + 1)*64 + row*8 + tid];
    float g8[8];
    #pragma unroll
    for (int c2 = 0; c2 < 8; ++c2) g8[c2] = 0.f;
    #pragma unroll
    for (int icl = 0; icl < 16; ++icl){
      const int icg = ih*16 + icl;
      const float* hb = &h_lds[icl*8 + hbase];
      f32x4v hv0 = *reinterpret_cast<const f32x4v*>(hb);
      f32x4v hv1 = *reinterpret_cast<const f32x4v*>(hb + 4);
      const float hv[8] = {hv0[0],hv0[1],hv0[2],hv0[3],hv1[0],hv1[1],hv1[2],hv1[3]};
      const f16* wq = &wlds[icg*3*128 + gc];
      const float wh0 = (float)wq[0];
      const float wh1 = (float)wq[128];
      const float wh2 = (float)wq[256];
      #pragma unroll
      for (int c2 = 0; c2 < 8; ++c2){
        float s = hv[c2] * wh1;
        if (c2 > 0) s += hv[c2-1] * wh0;
        if (c2 < 7) s += hv[c2+1] * wh2;
        g8[c2] += s;
      }
    }
    if (ih == 0){
      #pragma unroll
      for (int c2 = 0; c2 < 8; ++c2){
        float s = x_lds[c2] * wx1 + bsum;
        if (c2 > 0) s += x_lds[c2-1] * wx0;
        if (c2 < 7) s += x_lds[c2+1] * wx2;
        g8[c2] += s;
      }
    }
    #pragma unroll
    for (int c2 = 0; c2 < 8; ++c2) P[gc][ih][c2] = g8[c2];
    __syncthreads();
    const float ipre = P[ic   ][0][col] + P[ic   ][1][col];
    const float fpre = P[ic+32][0][col] + P[ic+32][1][col];
    const float opre = P[ic+64][0][col] + P[ic+64][1][col];
    const float gpre = P[ic+96][0][col] + P[ic+96][1][col];
    const float cn = sigmoidf_(fpre)*c_reg + sigmoidf_(ipre)*tanhf(gpre);
    c_reg = cn;
    const float hn = sigmoidf_(opre)*tanhf(cn);
    hrawHi[((size_t)t*128 + b)*2048 + row*256 + tid] = (f16)hn;
    __syncthreads();
    h_lds[wofs] = hn;
  }
}

// ---------------------------------------------------------------------------
// Batched x-convolution for layer 1, grid-parallel: block = (b,row, t-chunk
// of 8). All 8 x-rows staged up front, ONE barrier.
// ---------------------------------------------------------------------------
__global__ __launch_bounds__(256) void k_xconv(
    const f16* __restrict__ r0Hi, const f16* __restrict__ r0Lo,
    const unsigned short* __restrict__ wcx16,  // [(icg*3+j)*128+gc]
    f16* __restrict__ xg)                      // [T][B][8][128][8] f16
{
  const int b = blockIdx.x >> 3, row = blockIdx.x & 7;
  const int tc = blockIdx.y;                   // t-chunk: 8 steps
  const int tid = threadIdx.x;
  const int gc = tid >> 1, half = tid & 1;
  __shared__ float xs[8][256];
  __shared__ unsigned short wl[96*128];        // cx taps, 24 KB
  for (int i = tid; i < 96*128; i += 256) wl[i] = wcx16[i];
  const size_t dg = (size_t)b*2048 + row*256 + tid;
  #pragma unroll
  for (int tt = 0; tt < 8; ++tt){
    const size_t tb = (size_t)(tc*8 + tt)*BD + dg;
    xs[tt][tid] = (float)r0Hi[tb] + (float)r0Lo[tb];
  }
  __syncthreads();
  const int c0 = half*4;
  float acc0[8], acc1[8], acc2[8], acc3[8];
  #pragma unroll
  for (int tt = 0; tt < 8; ++tt){ acc0[tt]=0.f; acc1[tt]=0.f; acc2[tt]=0.f; acc3[tt]=0.f; }
  for (int ic2 = 0; ic2 < 32; ++ic2){
    const unsigned short* wq = &wl[ic2*3*128 + gc];
    const float wx0 = bf2f(wq[0]), wx1 = bf2f(wq[128]), wx2 = bf2f(wq[256]);
    #pragma unroll
    for (int tt = 0; tt < 8; ++tt){
      const float* xr = &xs[tt][ic2*8];
      {
        const int c = c0 + 0;
        float s = xr[c]*wx1;
        if (c > 0) s += xr[c-1]*wx0;
        s += xr[c+1]*wx2;
        acc0[tt] += s;
      }
      {
        const int c = c0 + 1;
        acc1[tt] += xr[c]*wx1 + xr[c-1]*wx0 + xr[c+1]*wx2;
      }
      {
        const int c = c0 + 2;
        acc2[tt] += xr[c]*wx1 + xr[c-1]*wx0 + xr[c+1]*wx2;
      }
      {
        const int c = c0 + 3;
        float s = xr[c]*wx1 + xr[c-1]*wx0;
        if (c < 7) s += xr[c+1]*wx2;
        acc3[tt] += s;
      }
    }
  }
  const size_t xgbase = ((size_t)b*8 + row)*1024 + gc*8 + half*4;
  #pragma unroll
  for (int tt = 0; tt < 8; ++tt){
    f16x4 o;
    o[0] = (f16)acc0[tt]; o[1] = (f16)acc1[tt];
    o[2] = (f16)acc2[tt]; o[3] = (f16)acc3[tt];
    *reinterpret_cast<f16x4*>(xg + (size_t)(tc*8 + tt)*XGT + xgbase) = o;
  }
}

// ---------------------------------------------------------------------------
// Layer-1 ConvLSTM for ALL 64 steps, h-conv only (x-conv precomputed in xg).
// ---------------------------------------------------------------------------
__global__ __launch_bounds__(256) void k_cell1_all(
    const f16* __restrict__ xg,                // [T][B][8][128][8]
    const float* __restrict__ h0s, const float* __restrict__ c0s,
    const unsigned short* __restrict__ wh16,   // [(icg*3+j)*128+gc]
    const float* __restrict__ cxb, const float* __restrict__ chb,
    f16* __restrict__ hrw1Hi)            // [T][B][2048]
{
  const int b = blockIdx.x >> 3, row = blockIdx.x & 7;
  const int tid = threadIdx.x;
  __shared__ float h_lds[264];
  __shared__ float P[128][2][9];
  __shared__ unsigned short wlds16[96*128];    // h taps only, 24 KB
  const int gc = tid >> 1, ih = tid & 1;
  for (int i = tid; i < 96*128; i += 256) wlds16[i] = wh16[i];
  const size_t dg = (size_t)b*2048 + row*256 + tid;
  const int ic = tid >> 3, col = tid & 7;
  const float bi = cxb[ic]    + chb[ic];
  const float bf = cxb[ic+32] + chb[ic+32];
  const float bo = cxb[ic+64] + chb[ic+64];
  const float bg = cxb[ic+96] + chb[ic+96];
  const int wofs = tid + ((tid >> 7) << 2);
  const int hbase = ih * 132;
  const size_t xgbase = ((size_t)b*8 + row)*1024 + gc*8;
  float c_reg = c0s[dg];
  h_lds[wofs] = h0s[dg];
  f16x8 xgv;
  if (ih == 0) xgv = *reinterpret_cast<const f16x8*>(xg + xgbase);
  __syncthreads();
  for (int t = 0; t < 64; ++t){
    f16x8 xgn;
    if (ih == 0 && t < 63)
      xgn = *reinterpret_cast<const f16x8*>(xg + (size_t)(t+1)*XGT + xgbase);
    {
      float g8[8];
      #pragma unroll
      for (int c2 = 0; c2 < 8; ++c2) g8[c2] = 0.f;
      #pragma unroll
      for (int icl = 0; icl < 16; ++icl){
        const int icg = ih*16 + icl;
        const float* hb = &h_lds[icl*8 + hbase];
        f32x4v hv0 = *reinterpret_cast<const f32x4v*>(hb);
        f32x4v hv1 = *reinterpret_cast<const f32x4v*>(hb + 4);
        const float hv[8] = {hv0[0],hv0[1],hv0[2],hv0[3],hv1[0],hv1[1],hv1[2],hv1[3]};
        const unsigned short* wq = &wlds16[icg*3*128 + gc];
        const float wh0 = bf2f(wq[0]);
        const float wh1 = bf2f(wq[128]);
        const float wh2 = bf2f(wq[256]);
        #pragma unroll
        for (int c2 = 0; c2 < 8; ++c2){
          float s = hv[c2]*wh1;
          if (c2 > 0) s += hv[c2-1]*wh0;
          if (c2 < 7) s += hv[c2+1]*wh2;
          g8[c2] += s;
        }
      }
      if (ih == 0){
        #pragma unroll
        for (int c2 = 0; c2 < 8; ++c2) g8[c2] += (float)xgv[c2];
      }
      #pragma unroll
      for (int c2 = 0; c2 < 8; ++c2) P[gc][ih][c2] = g8[c2];
    }
    __syncthreads();
    {
      const float ipre = P[ic   ][0][col] + P[ic   ][1][col] + bi;
      const float fpre = P[ic+32][0][col] + P[ic+32][1][col] + bf;
      const float opre = P[ic+64][0][col] + P[ic+64][1][col] + bo;
      const float gpre = P[ic+96][0][col] + P[ic+96][1][col] + bg;
      const float cn = sigmoidf_(fpre)*c_reg + sigmoidf_(ipre)*tanhf(gpre);
      c_reg = cn;
      const float hraw = sigmoidf_(opre)*tanhf(cn);
      hrw1Hi[(size_t)t*BD + dg] = (f16)hraw;
      __syncthreads();           // P reads done before next-iter overwrite
      h_lds[wofs] = hraw;
      if (ih == 0) xgv = xgn;
    }
  }
}

// ---------------------------------------------------------------------------
// MFMA inter-attention: block (b, t-half of 32). Writes ctx hi only.
// ---------------------------------------------------------------------------
__global__ __launch_bounds__(256) void k_attn(
    const f16* __restrict__ encF,    // [128][128][2048]
    const f16* __restrict__ encT,    // [128][2048][128]
    const f16* __restrict__ stHi,    // [T][B][2048]
    f16* __restrict__ ctxHi)         // [T][B][2048]
{
  const int b = blockIdx.x, th = blockIdx.y;
  const int tid = threadIdx.x, lane = tid & 63, wv = tid >> 6;
  __shared__ float S_lds[128][36];
  __shared__ float red[8][32];
  __shared__ float colv[32];
  __shared__ __align__(16) char aT[8192];
  const int kb = lane >> 5;
  // ---- phase 1
  {
    const int rA = wv*32 + (lane & 31);
    const int tcol = th*32 + (lane & 31);
    const f16* pA  = encF + ((size_t)b*128 + rA)*2048 + kb*8;
    const f16* pBH = stHi + ((size_t)tcol*128 + b)*2048 + kb*8;
    f32x16 acc;
    #pragma unroll
    for (int r = 0; r < 16; ++r) acc[r] = 0.f;
    #pragma unroll 4
    for (int s = 0; s < 128; ++s){
      f16x8 av = *reinterpret_cast<const f16x8*>(pA  + s*16);
      f16x8 bh = *reinterpret_cast<const f16x8*>(pBH + s*16);
      acc = __builtin_amdgcn_mfma_f32_32x32x16_f16(av, bh, acc, 0, 0, 0);
    }
    #pragma unroll
    for (int r = 0; r < 16; ++r){
      const int rr = 4*kb + (r & 3) + 8*(r >> 2);
      S_lds[wv*32 + rr][lane & 31] = acc[r];
    }
  }
  __syncthreads();
  // ---- phase 2: column softmax
  {
    const int c = tid & 31, g = tid >> 5;
    float ev[16];
    float m = -INFINITY;
    #pragma unroll
    for (int i = 0; i < 16; ++i){ ev[i] = S_lds[g*16 + i][c]; m = fmaxf(m, ev[i]); }
    red[g][c] = m;
    __syncthreads();
    if (tid < 32){
      float M = red[0][tid];
      #pragma unroll
      for (int j = 1; j < 8; ++j) M = fmaxf(M, red[j][tid]);
      colv[tid] = M;
    }
    __syncthreads();
    const float M = colv[c];
    float sum = 0.f;
    #pragma unroll
    for (int i = 0; i < 16; ++i){ ev[i] = __expf(ev[i] - M); sum += ev[i]; }
    __syncthreads();
    red[g][c] = sum;
    __syncthreads();
    if (tid < 32){
      float L = red[0][tid];
      #pragma unroll
      for (int j = 1; j < 8; ++j) L += red[j][tid];
      colv[tid] = 1.f / L;
    }
    __syncthreads();
    const float inv = colv[c];
    f16x8 w0, w1;
    #pragma unroll
    for (int j = 0; j < 8; ++j){
      w0[j] = (f16)(ev[j] * inv);
      w1[j] = (f16)(ev[8 + j] * inv);
    }
    const int sw = (c & 15) << 4;
    *reinterpret_cast<f16x8*>(aT + c*256 + (((g*2    )*16) ^ sw)) = w0;
    *reinterpret_cast<f16x8*>(aT + c*256 + (((g*2 + 1)*16) ^ sw)) = w1;
  }
  __syncthreads();
  // ---- phase 3
  {
    const int arow = lane & 31;
    const int asw = (arow & 15) << 4;
    f16x8 afr[8];
    #pragma unroll
    for (int ks = 0; ks < 8; ++ks){
      const int chunk = 2*ks + kb;
      afr[ks] = *reinterpret_cast<const f16x8*>(aT + arow*256 + ((chunk*16) ^ asw));
    }
    for (int nt = wv; nt < 64; nt += 4){
      const int d = nt*32 + (lane & 31);
      const f16* pB = encT + ((size_t)b*2048 + d)*128 + kb*8;
      f32x16 acc;
      #pragma unroll
      for (int r = 0; r < 16; ++r) acc[r] = 0.f;
      #pragma unroll
      for (int ks = 0; ks < 8; ++ks){
        f16x8 bv = *reinterpret_cast<const f16x8*>(pB + ks*16);
        acc = __builtin_amdgcn_mfma_f32_32x32x16_f16(afr[ks], bv, acc, 0, 0, 0);
      }
      #pragma unroll
      for (int r = 0; r < 16; ++r){
        const int rr = 4*kb + (r & 3) + 8*(r >> 2);
        const size_t o = ((size_t)(th*32 + rr)*128 + b)*2048 + d;
        ctxHi[o] = (f16)acc[r];
      }
    }
  }
}

// ---------------------------------------------------------------------------
// Batched full-K ia GEMM (all t): p[t] = tanh([A0|A1]@W + bias), f16 hi/lo.
// ---------------------------------------------------------------------------
__global__ __launch_bounds__(256, 2) void k_gemm_full(
    const f16* __restrict__ a0, const f16* __restrict__ a1,
    const f16* __restrict__ wHp, const float* __restrict__ bias,
    f16* __restrict__ outHi, f16* __restrict__ outLo)
{
  const int nt = blockIdx.x, t = blockIdx.y;
  const size_t tb = (size_t)t * BD;
  const int tid = threadIdx.x;
  const int lane = tid & 63, wv = tid >> 6;
  __shared__ __align__(16) char lds[49152];
  const f16* wH = wHp + (size_t)(nt*64)*4096;

  auto stage = [&](int buf, int ki){
    char* lb = lds + buf*24576;
    const f16* aH = ((ki < 32) ? a0 : a1) + tb;
    const int ke = (ki & 31) * 64;
    #pragma unroll
    for (int i = 0; i < 4; ++i){
      const int c = i*256 + tid, row = c >> 3;
      const int srcb = ((c & 7)*16) ^ ((row & 7) << 4);
      g2l16((const char*)(aH + (size_t)row*2048 + ke) + srcb, lb + c*16);
    }
    #pragma unroll
    for (int i = 0; i < 2; ++i){
      const int c = i*256 + tid, row = c >> 3;
      const int srcb = ((c & 7)*16) ^ ((row & 7) << 4);
      g2l16((const char*)(wH + (size_t)row*4096 + ki*64) + srcb, lb + 16384 + c*16);
    }
  };

  f32x16 acc0, acc1;
  #pragma unroll
  for (int r = 0; r < 16; ++r){ acc0[r] = 0.f; acc1[r] = 0.f; }
  const int rA = wv*32 + (lane & 31);
  const int kb = lane >> 5;
  const int rB0 = lane & 31;
  const int aswz = (rA & 7) << 4;
  const int bswz = (rB0 & 7) << 4;

  stage(0, 0);
  __syncthreads();
  for (int ki = 0; ki < 64; ++ki){
    const int buf = ki & 1;
    if (ki < 63) stage(buf ^ 1, ki + 1);
    const char* lb = lds + buf*24576;
    #pragma unroll
    for (int s = 0; s < 4; ++s){
      const int cb = s*32 + kb*16;
      f16x8 ah  = *reinterpret_cast<const f16x8*>(lb + rA*128 + (cb ^ aswz));
      f16x8 b0h = *reinterpret_cast<const f16x8*>(lb + 16384 + rB0*128 + (cb ^ bswz));
      f16x8 b1h = *reinterpret_cast<const f16x8*>(lb + 16384 + 4096 + rB0*128 + (cb ^ bswz));
      acc0 = __builtin_amdgcn_mfma_f32_32x32x16_f16(ah, b0h, acc0, 0, 0, 0);
      acc1 = __builtin_amdgcn_mfma_f32_32x32x16_f16(ah, b1h, acc1, 0, 0, 0);
    }
    __syncthreads();
  }

  const int col0 = nt*64 + (lane & 31);
  const float b0 = bias[col0], b1 = bias[col0 + 32];
  const int rowBase = wv*32 + 4*kb;
  #pragma unroll
  for (int r = 0; r < 16; ++r){
    const int rr = rowBase + (r & 3) + 8*(r >> 2);
    const size_t o = tb + (size_t)rr*2048 + col0;
    const float p = tanhf(acc0[r] + b0);
    const float q = tanhf(acc1[r] + b1);
    const f16 ph = (f16)p, qh = (f16)q;
    outHi[o]      = ph;  outLo[o]      = (f16)(p - (float)ph);
    outHi[o + 32] = qh;  outLo[o + 32] = (f16)(q - (float)qh);
  }
}

// ---------------------------------------------------------------------------
// Batched sa GEMM (all t): A = p hi (single pass), W = [Wlow^T|Wup^T].
// nt<32 -> Y (f32, raw); nt>=32 -> G (f16). Grid (64 nt, 64 t), K=2048.
// ---------------------------------------------------------------------------
__global__ __launch_bounds__(256, 2) void k_gemm_full2(
    const f16* __restrict__ aHi,                                // [T][B][2048]
    const f16* __restrict__ wSp,                                // [4096][2048]
    float* __restrict__ Y, f16* __restrict__ G)                 // [T][B][2048]
{
  const int nt = blockIdx.x, t = blockIdx.y;
  const size_t tb = (size_t)t * BD;
  const int tid = threadIdx.x;
  const int lane = tid & 63, wv = tid >> 6;
  __shared__ __align__(16) char lds[49152];
  const f16* wH = wSp + (size_t)(nt*64)*2048;
  const f16* aH = aHi + tb;

  auto stage = [&](int buf, int ki){
    char* lb = lds + buf*24576;
    const int ke = ki*64;
    #pragma unroll
    for (int i = 0; i < 4; ++i){
      const int c = i*256 + tid, row = c >> 3;
      const int srcb = ((c & 7)*16) ^ ((row & 7) << 4);
      g2l16((const char*)(aH + (size_t)row*2048 + ke) + srcb, lb + c*16);
    }
    #pragma unroll
    for (int i = 0; i < 2; ++i){
      const int c = i*256 + tid, row = c >> 3;
      const int srcb = ((c & 7)*16) ^ ((row & 7) << 4);
      g2l16((const char*)(wH + (size_t)row*2048 + ke) + srcb, lb + 16384 + c*16);
    }
  };

  f32x16 acc0, acc1;
  #pragma unroll
  for (int r = 0; r < 16; ++r){ acc0[r] = 0.f; acc1[r] = 0.f; }
  const int rA = wv*32 + (lane & 31);
  const int kb = lane >> 5;
  const int rB0 = lane & 31;
  const int aswz = (rA & 7) << 4;
  const int bswz = (rB0 & 7) << 4;

  stage(0, 0);
  __syncthreads();
  for (int ki = 0; ki < 32; ++ki){
    const int buf = ki & 1;
    if (ki < 31) stage(buf ^ 1, ki + 1);
    const char* lb = lds + buf*24576;
    #pragma unroll
    for (int s = 0; s < 4; ++s){
      const int cb = s*32 + kb*16;
      f16x8 ah  = *reinterpret_cast<const f16x8*>(lb + rA*128 + (cb ^ aswz));
      f16x8 b0h = *reinterpret_cast<const f16x8*>(lb + 16384 + rB0*128 + (cb ^ bswz));
      f16x8 b1h = *reinterpret_cast<const f16x8*>(lb + 16384 + 4096 + rB0*128 + (cb ^ bswz));
      acc0 = __builtin_amdgcn_mfma_f32_32x32x16_f16(ah, b0h, acc0, 0, 0, 0);
      acc1 = __builtin_amdgcn_mfma_f32_32x32x16_f16(ah, b1h, acc1, 0, 0, 0);
    }
    __syncthreads();
  }

  const int col0 = nt*64 + (lane & 31);
  const int rowBase = wv*32 + 4*kb;
  if (nt < 32){
    float* yp = Y + tb + col0;
    #pragma unroll
    for (int r = 0; r < 16; ++r){
      const int rr = rowBase + (r & 3) + 8*(r >> 2);
      yp[(size_t)rr*2048]      = acc0[r];
      yp[(size_t)rr*2048 + 32] = acc1[r];
    }
  } else {
    f16* gp = G + tb + (col0 - 2048);
    #pragma unroll
    for (int r = 0; r < 16; ++r){
      const int rr = rowBase + (r & 3) + 8*(r >> 2);
      gp[(size_t)rr*2048]      = (f16)acc0[r];
      gp[(size_t)rr*2048 + 32] = (f16)acc1[r];
    }
  }
}

// ---------------------------------------------------------------------------
// Self-attention refine chain (persistent over t). Block per b, 1024 threads
// (16 waves); G-sum unrolled x2; epilogue d0 = tid*2.
// ---------------------------------------------------------------------------
__global__ __launch_bounds__(1024) void k_selfchain(
    const f16* __restrict__ pHi, const f16* __restrict__ pLo,   // [T][B][2048]
    const float* __restrict__ Y, const f16* __restrict__ G,     // [T][B][2048]
    const float* __restrict__ bias,
    f16* __restrict__ rHi, f16* __restrict__ rLo)               // [T][B][2048]
{
  const int b = blockIdx.x;
  const int tid = threadIdx.x, lane = tid & 63, wv = tid >> 6;   // 16 waves
  __shared__ float sc[64];
  __shared__ float a_lds[64];
  const int d0 = tid * 2;
  f32x2v bb = *reinterpret_cast<const f32x2v*>(bias + d0);
  for (int t = 0; t < 64; ++t){
    const size_t pb = ((size_t)t*128 + b)*2048;
    if (t > 0){
      // each wave holds the full p[t] row (32 f32/lane)
      float hreg[32];
      #pragma unroll
      for (int jj = 0; jj < 4; ++jj){
        const int d = (jj*64 + lane)*8;
        f16x8 h8 = *reinterpret_cast<const f16x8*>(pHi + pb + d);
        f16x8 l8 = *reinterpret_cast<const f16x8*>(pLo + pb + d);
        #pragma unroll
        for (int j = 0; j < 8; ++j) hreg[jj*8+j] = (float)h8[j] + (float)l8[j];
      }
      for (int i = wv; i < t; i += 16){
        const f16* rh = rHi + ((size_t)i*128 + b)*2048;
        const f16* rl = rLo + ((size_t)i*128 + b)*2048;
        float dot = 0.f;
        #pragma unroll
        for (int jj = 0; jj < 4; ++jj){
          const int d = (jj*64 + lane)*8;
          f16x8 h8 = *reinterpret_cast<const f16x8*>(rh + d);
          f16x8 l8 = *reinterpret_cast<const f16x8*>(rl + d);
          #pragma unroll
          for (int j = 0; j < 8; ++j)
            dot += ((float)h8[j] + (float)l8[j]) * hreg[jj*8+j];
        }
        #pragma unroll
        for (int off = 1; off < 64; off <<= 1) dot += __shfl_xor(dot, off);
        if (lane == 0) sc[i] = dot;
      }
      __syncthreads();
      if (tid < 64){
        const float s = (tid < t) ? sc[tid] : -INFINITY;
        float mm = s;
        #pragma unroll
        for (int off = 1; off < 64; off <<= 1) mm = fmaxf(mm, __shfl_xor(mm, off));
        const float e = (tid < t) ? __expf(s - mm) : 0.f;
        float sum = e;
        #pragma unroll
        for (int off = 1; off < 64; off <<= 1) sum += __shfl_xor(sum, off);
        a_lds[tid] = e / sum;
      }
      __syncthreads();
    }
    float y0, y1;
    {
      f32x2v yv = *reinterpret_cast<const f32x2v*>(Y + (size_t)t*BD + (size_t)b*2048 + d0);
      y0 = yv[0] + bb[0];
      y1 = yv[1] + bb[1];
    }
    if (t > 0){
      // G-sum unrolled x2 with independent accumulators
      float z0 = 0.f, z1 = 0.f;
      int i = 0;
      for (; i + 1 < t; i += 2){
        const float a0 = a_lds[i], a1 = a_lds[i+1];
        f16x2 g0 = *reinterpret_cast<const f16x2*>(G + ((size_t)i*128 + b)*2048 + d0);
        f16x2 g1 = *reinterpret_cast<const f16x2*>(G + ((size_t)(i+1)*128 + b)*2048 + d0);
        y0 += a0 * (float)g0[0];
        y1 += a0 * (float)g0[1];
        z0 += a1 * (float)g1[0];
        z1 += a1 * (float)g1[1];
      }
      if (i < t){
        const float a0 = a_lds[i];
        f16x2 g0 = *reinterpret_cast<const f16x2*>(G + ((size_t)i*128 + b)*2048 + d0);
        y0 += a0 * (float)g0[0];
        y1 += a0 * (float)g0[1];
      }
      y0 += z0;
      y1 += z1;
    }
    f16x2 hh, ll;
    {
      const float v0 = tanhf(y0);
      const float v1 = tanhf(y1);
      hh[0] = (f16)v0; ll[0] = (f16)(v0 - (float)hh[0]);
      hh[1] = (f16)v1; ll[1] = (f16)(v1 - (float)hh[1]);
    }
    *reinterpret_cast<f16x2*>(rHi + pb + d0) = hh;
    *reinterpret_cast<f16x2*>(rLo + pb + d0) = ll;
    __syncthreads();   // r[t] stores drained before t+1 scores read them
  }
}

// ---------------------------------------------------------------------------
// Head stage 1: z1 = relu(r1(8192x2048) @ hw1 + hb1), single-pass f16 MFMA
// ---------------------------------------------------------------------------
__global__ __launch_bounds__(256) void k_headgemm(
    const f16* __restrict__ aHi,
    const f16* __restrict__ w1H,   // [224][2048]
    const float* __restrict__ hb1,
    float* __restrict__ z1)        // [8192][224]
{
  const int mb = blockIdx.x;
  const int nt = blockIdx.y;
  const int lane = threadIdx.x & 63, wv = threadIdx.x >> 6;
  const int rowA = mb*128 + wv*32 + (lane & 31);
  const int kb = lane >> 5;
  const int n = nt*32 + (lane & 31);
  const f16* pAH = aHi + (size_t)rowA*2048 + kb*8;
  const f16* pBH = w1H + (size_t)n*2048 + kb*8;
  f32x16 acc;
  #pragma unroll
  for (int r = 0; r < 16; ++r) acc[r] = 0.f;
  #pragma unroll 4
  for (int s = 0; s < 128; ++s){
    f16x8 ah = *reinterpret_cast<const f16x8*>(pAH + s*16);
    f16x8 bh = *reinterpret_cast<const f16x8*>(pBH + s*16);
    acc = __builtin_amdgcn_mfma_f32_32x32x16_f16(ah, bh, acc, 0, 0, 0);
  }
  const float bias = (n < 200) ? hb1[n] : 0.f;
  const int rowBase = mb*128 + wv*32 + 4*kb;
  #pragma unroll
  for (int r = 0; r < 16; ++r){
    const int rr = rowBase + (r & 3) + 8*(r >> 2);
    z1[(size_t)rr*224 + n] = fmaxf(acc[r] + bias, 0.f);
  }
}

// Head stage 2
__global__ __launch_bounds__(256) void k_head2(
    const float* __restrict__ z1,
    const float* __restrict__ hw2, const float* __restrict__ hb2,
    const float* __restrict__ hw3, const float* __restrict__ hb3,
    float* __restrict__ out)
{
  const int r0 = blockIdx.x * 64;
  const int tid = threadIdx.x;
  __shared__ float zl[64][200];
  __shared__ float z2[64][50];
  for (int i = tid; i < 64*200; i += 256){
    const int r = i / 200, n = i % 200;
    zl[r][n] = z1[(size_t)(r0 + r)*224 + n];
  }
  __syncthreads();
  for (int i = tid; i < 64*50; i += 256){
    const int r = i / 50, n = i % 50;
    float s = hb2[n];
    for (int k = 0; k < 200; ++k) s += zl[r][k] * hw2[k*50 + n];
    z2[r][n] = fmaxf(s, 0.f);
  }
  __syncthreads();
  for (int i = tid; i < 128; i += 256){
    const int r = i >> 1, c = i & 1;
    float s = hb3[c];
    for (int k = 0; k < 50; ++k) s += z2[r][k] * hw3[k*2 + c];
    const int rg = r0 + r;
    const int tt = rg >> 7, b = rg & 127;
    out[(size_t)b*128 + tt*2 + c] = s;
  }
}

// ---------------------------------------------------------------------------
extern "C" void kernel_launch(void* const* d_in, const int* in_sizes, int n_in,
                              void* d_out, int out_size, void* d_ws, size_t ws_size,
                              hipStream_t stream)
{
  (void)in_sizes; (void)n_in; (void)out_size; (void)ws_size;
  const float* x_flat = (const float*)d_in[0];
  const float* enc    = (const float*)d_in[1];
  const float* h0     = (const float*)d_in[2];
  const float* c0     = (const float*)d_in[3];
  const float* cx_w0  = (const float*)d_in[4];
  const float* cx_b0  = (const float*)d_in[5];
  const float* ch_w0  = (const float*)d_in[6];
  const float* ch_b0  = (const float*)d_in[7];
  const float* cx_w1  = (const float*)d_in[8];
  const float* cx_b1  = (const float*)d_in[9];
  const float* ch_w1  = (const float*)d_in[10];
  const float* ch_b1  = (const float*)d_in[11];
  const float* ia_w0  = (const float*)d_in[12];
  const float* ia_b0  = (const float*)d_in[13];
  const float* sa_w0  = (const float*)d_in[14];
  const float* sa_b0  = (const float*)d_in[15];
  const float* ia_w1  = (const float*)d_in[16];
  const float* ia_b1  = (const float*)d_in[17];
  const float* sa_w1  = (const float*)d_in[18];
  const float* sa_b1  = (const float*)d_in[19];
  const float* hw1    = (const float*)d_in[20];
  const float* hb1    = (const float*)d_in[21];
  const float* hw2    = (const float*)d_in[22];
  const float* hb2    = (const float*)d_in[23];
  const float* hw3    = (const float*)d_in[24];
  const float* hb3    = (const float*)d_in[25];
  float* out = (float*)d_out;

  char* ws = (char*)d_ws;
  size_t off = 0;
  auto alloc = [&](size_t bytes) -> char* {
    char* p = ws + off;
    off += (bytes + 255) & ~(size_t)255;
    return p;
  };
  const size_t WPLANE = (size_t)2048*4096*2;   // 16 MiB
  const size_t TPLANE = (size_t)64*BD*2;       // 32 MiB, [T][B][D] f16
  f16* wIa0 = (f16*)alloc(WPLANE);
  f16* wSa0 = (f16*)alloc(WPLANE);   // [4096][2048]: Wlow^T rows 0..2047, Wup^T rows 2048..
  f16* wIa1 = (f16*)alloc(WPLANE);
  f16* wSa1 = (f16*)alloc(WPLANE);
  f16* w1H  = (f16*)alloc((size_t)224*2048*2);
  f16* encF = (f16*)alloc((size_t)128*128*2048*2);   // 64 MiB
  f16* encT = (f16*)alloc((size_t)128*2048*128*2);   // 64 MiB
  f16* S1 = (f16*)alloc(TPLANE);
  f16* S2 = (f16*)alloc(TPLANE);
  f16* S3 = (f16*)alloc(TPLANE);
  f16* S4 = (f16*)alloc(TPLANE);
  f16* S5 = (f16*)alloc(TPLANE);
  f16* S6 = (f16*)alloc(TPLANE);
  f16* S7 = (f16*)alloc(TPLANE);
  f16* S8 = (f16*)alloc(TPLANE);
  unsigned short* wh16  = (unsigned short*)alloc((size_t)96*128*2);
  unsigned short* wcx16 = (unsigned short*)alloc((size_t)96*128*2);
  f16* w0h16 = (f16*)alloc((size_t)96*128*2);
  // total ws ~= 449 MiB. Alias names (lifetimes verified disjoint):
  f16*  hr0AHi = S1;                         // layer-0 raw h (hi only)
  f16*  ctx0Hi = S3;
  f16*  p0Hi   = S5;  f16* p0Lo   = S6;
  float* Y0 = (float*)S1;                    // 64 MiB over S1+S2 (contiguous)
  f16*  G0  = S3;
  f16*  r0Hi = S7;    f16* r0Lo   = S8;
  f16*  xgb  = S1;                           // 128 MiB over S1..S4 (contiguous);
                                             // live [k_xconv, k_cell1_all] only
  f16*  hrw1Hi = S5;                         // hi only
  f16*  ctx1Hi = S1;
  f16*  p1Hi = S7;    f16* p1Lo   = S8;
  float* Y1 = (float*)S1;                    // 64 MiB over S1+S2
  f16*  G1  = S4;
  f16*  r1Hi = S5;    f16* r1Lo   = S3;
  float* z1 = (float*)wSa0;                  // head scratch (wSa0 dead by then)

  // ---- prologue -----------------------------------------------------------
  k_transpose_f16<<<dim3(64,128),256,0,stream>>>(ia_w0, wIa0, 4096, 2048);
  k_transpose_f16<<<dim3(64,128),256,0,stream>>>(ia_w1, wIa1, 4096, 2048);
  k_transpose_f16<<<dim3(64,64),256,0,stream>>>(sa_w0, wSa0, 2048, 2048);
  k_transpose_f16<<<dim3(64,64),256,0,stream>>>(sa_w0 + (size_t)2048*2048,
                                                wSa0 + (size_t)2048*2048, 2048, 2048);
  k_transpose_f16<<<dim3(64,64),256,0,stream>>>(sa_w1, wSa1, 2048, 2048);
  k_transpose_f16<<<dim3(64,64),256,0,stream>>>(sa_w1 + (size_t)2048*2048,
                                                wSa1 + (size_t)2048*2048, 2048, 2048);
  k_transpose_f16<<<dim3(7,64),256,0,stream>>>(hw1, w1H, 2048, 200);
  k_enc_prep<<<dim3(64,4,128),256,0,stream>>>(enc, encF, encT);
  k_pack_cellw<<<16,256,0,stream>>>(ch_w1, cx_w1, wh16, wcx16);
  k_pack_cellw0<<<16,256,0,stream>>>(ch_w0, w0h16);

  // ---- layer 0 (fully batched + one persistent chain) ---------------------
  k_cell0<<<1024,256,0,stream>>>(x_flat, h0, c0, cx_w0, cx_b0, w0h16, ch_b0,
                                 hr0AHi);
  k_attn<<<dim3(128,2),256,0,stream>>>(encF, encT, hr0AHi, ctx0Hi);
  k_gemm_full<<<dim3(32,64),256,0,stream>>>(hr0AHi, ctx0Hi,
                                            wIa0, ia_b0, p0Hi, p0Lo);
  k_gemm_full2<<<dim3(64,64),256,0,stream>>>(p0Hi, wSa0, Y0, G0);
  k_selfchain<<<128,1024,0,stream>>>(p0Hi, p0Lo, Y0, G0, sa_b0, r0Hi, r0Lo);

  // ---- layer 1: grid-parallel x-conv, persistent h-cell, batched rest -----
  k_xconv<<<dim3(1024,8),256,0,stream>>>(r0Hi, r0Lo, wcx16, xgb);
  k_cell1_all<<<1024,256,0,stream>>>(xgb,
                                     h0 + (size_t)128*2048, c0 + (size_t)128*2048,
                                     wh16, cx_b1, ch_b1, hrw1Hi);
  k_attn<<<dim3(128,2),256,0,stream>>>(encF, encT, hrw1Hi, ctx1Hi);
  k_gemm_full<<<dim3(32,64),256,0,stream>>>(hrw1Hi, ctx1Hi,
                                            wIa1, ia_b1, p1Hi, p1Lo);
  k_gemm_full2<<<dim3(64,64),256,0,stream>>>(p1Hi, wSa1, Y1, G1);
  k_selfchain<<<128,1024,0,stream>>>(p1Hi, p1Lo, Y1, G1, sa_b1, r1Hi, r1Lo);

  // ---- head (batched over all t,b) ----------------------------------------
  k_headgemm<<<dim3(64,7),256,0,stream>>>(r1Hi, w1H, hb1, z1);
  k_head2<<<128,256,0,stream>>>(z1, hw2, hb2, hw3, hb3, out);
}

// Round 19
// 2951.398 us; speedup vs baseline: 1.2927x; 1.1645x over previous
//
#include <hip/hip_runtime.h>
#include <math.h>

// ---------------------------------------------------------------------------
// CLSADecoder: 2-layer RowSharedConvLSTM + inter-attn + causal self-attn + head
// B=128, T=64, D=2048 (ROWS=8, CH=32, COLS=8), S=128.
// R18: selfchain traffic diet. (a) score dots use hi-only r/p (f16 precision
// suffices for tanh-bounded states; lo-compensation was a bf16-era artifact)
// -> score traffic halved, pLo planes dead -> gemm_full stops writing outLo.
// (b) G rows 0..31 (the most-reused: 32-63 reads each) cached in 128KB LDS
// once per block -> G global traffic 8.06->2.1MB per b. Grid is 128 blocks
// (<=1/CU) so the big LDS footprint costs no occupancy.
// ---------------------------------------------------------------------------

typedef _Float16 f16;
typedef _Float16 f16x8 __attribute__((ext_vector_type(8)));
typedef _Float16 f16x4 __attribute__((ext_vector_type(4)));
typedef _Float16 f16x2 __attribute__((ext_vector_type(2)));
typedef float  f32x16 __attribute__((ext_vector_type(16)));
typedef float  f32x4v __attribute__((ext_vector_type(4)));
typedef float  f32x2v __attribute__((ext_vector_type(2)));
typedef unsigned short u16x8 __attribute__((ext_vector_type(8)));
typedef unsigned short u16x4 __attribute__((ext_vector_type(4)));

#define BD 262144   // 128*2048  (one [B][D] plane)
#define XGT 1048576 // xg per-t stride: 128*8*1024 elements

__device__ __forceinline__ unsigned short f2bf(float x){
  unsigned int u = __builtin_bit_cast(unsigned int, x);
  u += 0x7fffu + ((u >> 16) & 1u);
  return (unsigned short)(u >> 16);
}
__device__ __forceinline__ float bf2f(unsigned short h){
  unsigned int u = ((unsigned int)h) << 16;
  return __builtin_bit_cast(float, u);
}
__device__ __forceinline__ float sigmoidf_(float x){
  return 1.0f / (1.0f + __expf(-x));
}
__device__ __forceinline__ void g2l16(const void* g, void* l){
  __builtin_amdgcn_global_load_lds(
      (const __attribute__((address_space(1))) unsigned int*)g,
      (__attribute__((address_space(3))) unsigned int*)l,
      16, 0, 0);
}

// ---------------------------------------------------------------------------
// transpose f32 weight [K][N] -> f16 plane [N][K]
// ---------------------------------------------------------------------------
__global__ __launch_bounds__(256) void k_transpose_f16(
    const float* __restrict__ src, f16* __restrict__ dhi,
    const int K, const int N)
{
  __shared__ float tile[32][33];
  const int n0 = blockIdx.x * 32, k0 = blockIdx.y * 32;
  const int tx = threadIdx.x & 31, ty = threadIdx.x >> 5;
  #pragma unroll
  for (int ii = 0; ii < 4; ++ii){
    const int k = k0 + ty + ii*8, n = n0 + tx;
    float v = (n < N) ? src[(size_t)k * N + n] : 0.0f;
    tile[ty + ii*8][tx] = v;
  }
  __syncthreads();
  #pragma unroll
  for (int ii = 0; ii < 4; ++ii){
    const int n = n0 + ty + ii*8, k = k0 + tx;
    dhi[(size_t)n * K + k] = (f16)tile[tx][ty + ii*8];
  }
}

// enc f32 -> encF (f16, [b][s][d]) and encT (f16, [b][d][s])
__global__ __launch_bounds__(256) void k_enc_prep(
    const float* __restrict__ enc,
    f16* __restrict__ encF, f16* __restrict__ encT)
{
  __shared__ float tile[32][33];
  const int dt = blockIdx.x;   // 0..63
  const int st = blockIdx.y;   // 0..3
  const int b  = blockIdx.z;   // 0..127
  const int tx = threadIdx.x & 31, ty = threadIdx.x >> 5;
  const int d0 = dt*32, s0 = st*32;
  #pragma unroll
  for (int ii = 0; ii < 4; ++ii){
    const int s = s0 + ty + ii*8, d = d0 + tx;
    const float v = enc[((size_t)b*128 + s)*2048 + d];
    tile[ty + ii*8][tx] = v;
    encF[((size_t)b*128 + s)*2048 + d] = (f16)v;
  }
  __syncthreads();
  #pragma unroll
  for (int ii = 0; ii < 4; ++ii){
    const int d = d0 + ty + ii*8, s = s0 + tx;
    encT[((size_t)b*2048 + d)*128 + s] = (f16)tile[tx][ty + ii*8];
  }
}

// split cell1 conv weights: wh16[(icg*3+j)*128+gc] (h taps),
// wcx16[(icg*3+j)*128+gc] (x taps), bf16.
__global__ void k_pack_cellw(const float* __restrict__ chw,
                             const float* __restrict__ cxw,
                             unsigned short* __restrict__ wh16,
                             unsigned short* __restrict__ wcx16)
{
  const int i = blockIdx.x * 256 + threadIdx.x;   // i = gc*32 + icg
  if (i < 128 * 32){
    const int gc = i >> 5, icg = i & 31;
    #pragma unroll
    for (int k = 0; k < 3; ++k){
      wh16[(icg*3 + k)*128 + gc]  = f2bf(chw[i*3 + k]);
      wcx16[(icg*3 + k)*128 + gc] = f2bf(cxw[i*3 + k]);
    }
  }
}

// cell0 h-taps -> f16 table w0h16[(icg*3+j)*128+gc]
__global__ void k_pack_cellw0(const float* __restrict__ chw,
                              f16* __restrict__ w0h16)
{
  const int i = blockIdx.x * 256 + threadIdx.x;   // i = gc*32 + icg
  if (i < 128 * 32){
    const int gc = i >> 5, icg = i & 31;
    #pragma unroll
    for (int k = 0; k < 3; ++k)
      w0h16[(icg*3 + k)*128 + gc] = (f16)chw[i*3 + k];
  }
}

// ---------------------------------------------------------------------------
// Layer-0 ConvLSTM for ALL 64 steps. Block=(b,row). Writes hraw hi only.
// ---------------------------------------------------------------------------
__global__ __launch_bounds__(256) void k_cell0(
    const float* __restrict__ x_flat,
    const float* __restrict__ h0, const float* __restrict__ c0,
    const float* __restrict__ cxw, const float* __restrict__ cxb,
    const f16* __restrict__ w0h16, const float* __restrict__ chb,
    f16* __restrict__ hrawHi)     // [T][B][2048]
{
  const int b = blockIdx.x >> 3, row = blockIdx.x & 7;
  const int tid = threadIdx.x;
  __shared__ float h_lds[264];
  __shared__ float x_lds[8];
  __shared__ float P[128][2][9];
  __shared__ f16 wlds[96*128];                 // h taps, 24 KB
  const int gc = tid >> 1, ih = tid & 1;
  for (int i = tid; i < 96*128; i += 256) wlds[i] = w0h16[i];
  const float wx0 = cxw[gc*3+0], wx1 = cxw[gc*3+1], wx2 = cxw[gc*3+2];
  const float bsum = cxb[gc] + chb[gc];
  const int ic = tid >> 3, col = tid & 7;
  const size_t dg = (size_t)b*2048 + row*256 + tid;
  const int wofs = tid + ((tid >> 7) << 2);
  const int hbase = ih * 132;
  float c_reg = c0[dg];
  h_lds[wofs] = h0[dg];
  float xnext = (tid < 8) ? x_flat[((size_t)b*64 + 0)*64 + row*8 + tid] : 0.f;
  __syncthreads();
  for (int t = 0; t < 64; ++t){
    if (tid < 8) x_lds[tid] = xnext;
    __syncthreads();
    if (t < 63 && tid < 8)
      xnext = x_flat[((size_t)b*64 + t + 1)*64 + row*8 + tid];
    float g8[8];
    #pragma unroll
    for (int c2 = 0; c2 < 8; ++c2) g8[c2] = 0.f;
    #pragma unroll
    for (int icl = 0; icl < 16; ++icl){
      const int icg = ih*16 + icl;
      const float* hb = &h_lds[icl*8 + hbase];
      f32x4v hv0 = *reinterpret_cast<const f32x4v*>(hb);
      f32x4v hv1 = *reinterpret_cast<const f32x4v*>(hb + 4);
      const float hv[8] = {hv0[0],hv0[1],hv0[2],hv0[3],hv1[0],hv1[1],hv1[2],hv1[3]};
      const f16* wq = &wlds[icg*3*128 + gc];
      const float wh0 = (float)wq[0];
      const float wh1 = (float)wq[128];
      const float wh2 = (float)wq[256];
      #pragma unroll
      for (int c2 = 0; c2 < 8; ++c2){
        float s = hv[c2] * wh1;
        if (c2 > 0) s += hv[c2-1] * wh0;
        if (c2 < 7) s += hv[c2+1] * wh2;
        g8[c2] += s;
      }
    }
    if (ih == 0){
      #pragma unroll
      for (int c2 = 0; c2 < 8; ++c2){
        float s = x_lds[c2] * wx1 + bsum;
        if (c2 > 0) s += x_lds[c2-1] * wx0;
        if (c2 < 7) s += x_lds[c2+1] * wx2;
        g8[c2] += s;
      }
    }
    #pragma unroll
    for (int c2 = 0; c2 < 8; ++c2) P[gc][ih][c2] = g8[c2];
    __syncthreads();
    const float ipre = P[ic   ][0][col] + P[ic   ][1][col];
    const float fpre = P[ic+32][0][col] + P[ic+32][1][col];
    const float opre = P[ic+64][0][col] + P[ic+64][1][col];
    const float gpre = P[ic+96][0][col] + P[ic+96][1][col];
    const float cn = sigmoidf_(fpre)*c_reg + sigmoidf_(ipre)*tanhf(gpre);
    c_reg = cn;
    const float hn = sigmoidf_(opre)*tanhf(cn);
    hrawHi[((size_t)t*128 + b)*2048 + row*256 + tid] = (f16)hn;
    __syncthreads();
    h_lds[wofs] = hn;
  }
}

// ---------------------------------------------------------------------------
// Batched x-convolution for layer 1, grid-parallel.
// ---------------------------------------------------------------------------
__global__ __launch_bounds__(256) void k_xconv(
    const f16* __restrict__ r0Hi, const f16* __restrict__ r0Lo,
    const unsigned short* __restrict__ wcx16,  // [(icg*3+j)*128+gc]
    f16* __restrict__ xg)                      // [T][B][8][128][8] f16
{
  const int b = blockIdx.x >> 3, row = blockIdx.x & 7;
  const int tc = blockIdx.y;                   // t-chunk: 8 steps
  const int tid = threadIdx.x;
  const int gc = tid >> 1, half = tid & 1;
  __shared__ float xs[8][256];
  __shared__ unsigned short wl[96*128];        // cx taps, 24 KB
  for (int i = tid; i < 96*128; i += 256) wl[i] = wcx16[i];
  const size_t dg = (size_t)b*2048 + row*256 + tid;
  #pragma unroll
  for (int tt = 0; tt < 8; ++tt){
    const size_t tb = (size_t)(tc*8 + tt)*BD + dg;
    xs[tt][tid] = (float)r0Hi[tb] + (float)r0Lo[tb];
  }
  __syncthreads();
  const int c0 = half*4;
  float acc0[8], acc1[8], acc2[8], acc3[8];
  #pragma unroll
  for (int tt = 0; tt < 8; ++tt){ acc0[tt]=0.f; acc1[tt]=0.f; acc2[tt]=0.f; acc3[tt]=0.f; }
  for (int ic2 = 0; ic2 < 32; ++ic2){
    const unsigned short* wq = &wl[ic2*3*128 + gc];
    const float wx0 = bf2f(wq[0]), wx1 = bf2f(wq[128]), wx2 = bf2f(wq[256]);
    #pragma unroll
    for (int tt = 0; tt < 8; ++tt){
      const float* xr = &xs[tt][ic2*8];
      {
        const int c = c0 + 0;
        float s = xr[c]*wx1;
        if (c > 0) s += xr[c-1]*wx0;
        s += xr[c+1]*wx2;
        acc0[tt] += s;
      }
      {
        const int c = c0 + 1;
        acc1[tt] += xr[c]*wx1 + xr[c-1]*wx0 + xr[c+1]*wx2;
      }
      {
        const int c = c0 + 2;
        acc2[tt] += xr[c]*wx1 + xr[c-1]*wx0 + xr[c+1]*wx2;
      }
      {
        const int c = c0 + 3;
        float s = xr[c]*wx1 + xr[c-1]*wx0;
        if (c < 7) s += xr[c+1]*wx2;
        acc3[tt] += s;
      }
    }
  }
  const size_t xgbase = ((size_t)b*8 + row)*1024 + gc*8 + half*4;
  #pragma unroll
  for (int tt = 0; tt < 8; ++tt){
    f16x4 o;
    o[0] = (f16)acc0[tt]; o[1] = (f16)acc1[tt];
    o[2] = (f16)acc2[tt]; o[3] = (f16)acc3[tt];
    *reinterpret_cast<f16x4*>(xg + (size_t)(tc*8 + tt)*XGT + xgbase) = o;
  }
}

// ---------------------------------------------------------------------------
// Layer-1 ConvLSTM for ALL 64 steps, h-conv only.
// ---------------------------------------------------------------------------
__global__ __launch_bounds__(256) void k_cell1_all(
    const f16* __restrict__ xg,                // [T][B][8][128][8]
    const float* __restrict__ h0s, const float* __restrict__ c0s,
    const unsigned short* __restrict__ wh16,   // [(icg*3+j)*128+gc]
    const float* __restrict__ cxb, const float* __restrict__ chb,
    f16* __restrict__ hrw1Hi)            // [T][B][2048]
{
  const int b = blockIdx.x >> 3, row = blockIdx.x & 7;
  const int tid = threadIdx.x;
  __shared__ float h_lds[264];
  __shared__ float P[128][2][9];
  __shared__ unsigned short wlds16[96*128];    // h taps only, 24 KB
  const int gc = tid >> 1, ih = tid & 1;
  for (int i = tid; i < 96*128; i += 256) wlds16[i] = wh16[i];
  const size_t dg = (size_t)b*2048 + row*256 + tid;
  const int ic = tid >> 3, col = tid & 7;
  const float bi = cxb[ic]    + chb[ic];
  const float bf = cxb[ic+32] + chb[ic+32];
  const float bo = cxb[ic+64] + chb[ic+64];
  const float bg = cxb[ic+96] + chb[ic+96];
  const int wofs = tid + ((tid >> 7) << 2);
  const int hbase = ih * 132;
  const size_t xgbase = ((size_t)b*8 + row)*1024 + gc*8;
  float c_reg = c0s[dg];
  h_lds[wofs] = h0s[dg];
  f16x8 xgv;
  if (ih == 0) xgv = *reinterpret_cast<const f16x8*>(xg + xgbase);
  __syncthreads();
  for (int t = 0; t < 64; ++t){
    f16x8 xgn;
    if (ih == 0 && t < 63)
      xgn = *reinterpret_cast<const f16x8*>(xg + (size_t)(t+1)*XGT + xgbase);
    {
      float g8[8];
      #pragma unroll
      for (int c2 = 0; c2 < 8; ++c2) g8[c2] = 0.f;
      #pragma unroll
      for (int icl = 0; icl < 16; ++icl){
        const int icg = ih*16 + icl;
        const float* hb = &h_lds[icl*8 + hbase];
        f32x4v hv0 = *reinterpret_cast<const f32x4v*>(hb);
        f32x4v hv1 = *reinterpret_cast<const f32x4v*>(hb + 4);
        const float hv[8] = {hv0[0],hv0[1],hv0[2],hv0[3],hv1[0],hv1[1],hv1[2],hv1[3]};
        const unsigned short* wq = &wlds16[icg*3*128 + gc];
        const float wh0 = bf2f(wq[0]);
        const float wh1 = bf2f(wq[128]);
        const float wh2 = bf2f(wq[256]);
        #pragma unroll
        for (int c2 = 0; c2 < 8; ++c2){
          float s = hv[c2]*wh1;
          if (c2 > 0) s += hv[c2-1]*wh0;
          if (c2 < 7) s += hv[c2+1]*wh2;
          g8[c2] += s;
        }
      }
      if (ih == 0){
        #pragma unroll
        for (int c2 = 0; c2 < 8; ++c2) g8[c2] += (float)xgv[c2];
      }
      #pragma unroll
      for (int c2 = 0; c2 < 8; ++c2) P[gc][ih][c2] = g8[c2];
    }
    __syncthreads();
    {
      const float ipre = P[ic   ][0][col] + P[ic   ][1][col] + bi;
      const float fpre = P[ic+32][0][col] + P[ic+32][1][col] + bf;
      const float opre = P[ic+64][0][col] + P[ic+64][1][col] + bo;
      const float gpre = P[ic+96][0][col] + P[ic+96][1][col] + bg;
      const float cn = sigmoidf_(fpre)*c_reg + sigmoidf_(ipre)*tanhf(gpre);
      c_reg = cn;
      const float hraw = sigmoidf_(opre)*tanhf(cn);
      hrw1Hi[(size_t)t*BD + dg] = (f16)hraw;
      __syncthreads();
      h_lds[wofs] = hraw;
      if (ih == 0) xgv = xgn;
    }
  }
}

// ---------------------------------------------------------------------------
// MFMA inter-attention: block (b, t-half of 32). Writes ctx hi only.
// ---------------------------------------------------------------------------
__global__ __launch_bounds__(256) void k_attn(
    const f16* __restrict__ encF,    // [128][128][2048]
    const f16* __restrict__ encT,    // [128][2048][128]
    const f16* __restrict__ stHi,    // [T][B][2048]
    f16* __restrict__ ctxHi)         // [T][B][2048]
{
  const int b = blockIdx.x, th = blockIdx.y;
  const int tid = threadIdx.x, lane = tid & 63, wv = tid >> 6;
  __shared__ float S_lds[128][36];
  __shared__ float red[8][32];
  __shared__ float colv[32];
  __shared__ __align__(16) char aT[8192];
  const int kb = lane >> 5;
  // ---- phase 1
  {
    const int rA = wv*32 + (lane & 31);
    const int tcol = th*32 + (lane & 31);
    const f16* pA  = encF + ((size_t)b*128 + rA)*2048 + kb*8;
    const f16* pBH = stHi + ((size_t)tcol*128 + b)*2048 + kb*8;
    f32x16 acc;
    #pragma unroll
    for (int r = 0; r < 16; ++r) acc[r] = 0.f;
    #pragma unroll 4
    for (int s = 0; s < 128; ++s){
      f16x8 av = *reinterpret_cast<const f16x8*>(pA  + s*16);
      f16x8 bh = *reinterpret_cast<const f16x8*>(pBH + s*16);
      acc = __builtin_amdgcn_mfma_f32_32x32x16_f16(av, bh, acc, 0, 0, 0);
    }
    #pragma unroll
    for (int r = 0; r < 16; ++r){
      const int rr = 4*kb + (r & 3) + 8*(r >> 2);
      S_lds[wv*32 + rr][lane & 31] = acc[r];
    }
  }
  __syncthreads();
  // ---- phase 2: column softmax
  {
    const int c = tid & 31, g = tid >> 5;
    float ev[16];
    float m = -INFINITY;
    #pragma unroll
    for (int i = 0; i < 16; ++i){ ev[i] = S_lds[g*16 + i][c]; m = fmaxf(m, ev[i]); }
    red[g][c] = m;
    __syncthreads();
    if (tid < 32){
      float M = red[0][tid];
      #pragma unroll
      for (int j = 1; j < 8; ++j) M = fmaxf(M, red[j][tid]);
      colv[tid] = M;
    }
    __syncthreads();
    const float M = colv[c];
    float sum = 0.f;
    #pragma unroll
    for (int i = 0; i < 16; ++i){ ev[i] = __expf(ev[i] - M); sum += ev[i]; }
    __syncthreads();
    red[g][c] = sum;
    __syncthreads();
    if (tid < 32){
      float L = red[0][tid];
      #pragma unroll
      for (int j = 1; j < 8; ++j) L += red[j][tid];
      colv[tid] = 1.f / L;
    }
    __syncthreads();
    const float inv = colv[c];
    f16x8 w0, w1;
    #pragma unroll
    for (int j = 0; j < 8; ++j){
      w0[j] = (f16)(ev[j] * inv);
      w1[j] = (f16)(ev[8 + j] * inv);
    }
    const int sw = (c & 15) << 4;
    *reinterpret_cast<f16x8*>(aT + c*256 + (((g*2    )*16) ^ sw)) = w0;
    *reinterpret_cast<f16x8*>(aT + c*256 + (((g*2 + 1)*16) ^ sw)) = w1;
  }
  __syncthreads();
  // ---- phase 3
  {
    const int arow = lane & 31;
    const int asw = (arow & 15) << 4;
    f16x8 afr[8];
    #pragma unroll
    for (int ks = 0; ks < 8; ++ks){
      const int chunk = 2*ks + kb;
      afr[ks] = *reinterpret_cast<const f16x8*>(aT + arow*256 + ((chunk*16) ^ asw));
    }
    for (int nt = wv; nt < 64; nt += 4){
      const int d = nt*32 + (lane & 31);
      const f16* pB = encT + ((size_t)b*2048 + d)*128 + kb*8;
      f32x16 acc;
      #pragma unroll
      for (int r = 0; r < 16; ++r) acc[r] = 0.f;
      #pragma unroll
      for (int ks = 0; ks < 8; ++ks){
        f16x8 bv = *reinterpret_cast<const f16x8*>(pB + ks*16);
        acc = __builtin_amdgcn_mfma_f32_32x32x16_f16(afr[ks], bv, acc, 0, 0, 0);
      }
      #pragma unroll
      for (int r = 0; r < 16; ++r){
        const int rr = 4*kb + (r & 3) + 8*(r >> 2);
        const size_t o = ((size_t)(th*32 + rr)*128 + b)*2048 + d;
        ctxHi[o] = (f16)acc[r];
      }
    }
  }
}

// ---------------------------------------------------------------------------
// Batched full-K ia GEMM (all t): p[t] = tanh([A0|A1]@W + bias), f16 hi only.
// ---------------------------------------------------------------------------
__global__ __launch_bounds__(256, 2) void k_gemm_full(
    const f16* __restrict__ a0, const f16* __restrict__ a1,
    const f16* __restrict__ wHp, const float* __restrict__ bias,
    f16* __restrict__ outHi)
{
  const int nt = blockIdx.x, t = blockIdx.y;
  const size_t tb = (size_t)t * BD;
  const int tid = threadIdx.x;
  const int lane = tid & 63, wv = tid >> 6;
  __shared__ __align__(16) char lds[49152];
  const f16* wH = wHp + (size_t)(nt*64)*4096;

  auto stage = [&](int buf, int ki){
    char* lb = lds + buf*24576;
    const f16* aH = ((ki < 32) ? a0 : a1) + tb;
    const int ke = (ki & 31) * 64;
    #pragma unroll
    for (int i = 0; i < 4; ++i){
      const int c = i*256 + tid, row = c >> 3;
      const int srcb = ((c & 7)*16) ^ ((row & 7) << 4);
      g2l16((const char*)(aH + (size_t)row*2048 + ke) + srcb, lb + c*16);
    }
    #pragma unroll
    for (int i = 0; i < 2; ++i){
      const int c = i*256 + tid, row = c >> 3;
      const int srcb = ((c & 7)*16) ^ ((row & 7) << 4);
      g2l16((const char*)(wH + (size_t)row*4096 + ki*64) + srcb, lb + 16384 + c*16);
    }
  };

  f32x16 acc0, acc1;
  #pragma unroll
  for (int r = 0; r < 16; ++r){ acc0[r] = 0.f; acc1[r] = 0.f; }
  const int rA = wv*32 + (lane & 31);
  const int kb = lane >> 5;
  const int rB0 = lane & 31;
  const int aswz = (rA & 7) << 4;
  const int bswz = (rB0 & 7) << 4;

  stage(0, 0);
  __syncthreads();
  for (int ki = 0; ki < 64; ++ki){
    const int buf = ki & 1;
    if (ki < 63) stage(buf ^ 1, ki + 1);
    const char* lb = lds + buf*24576;
    #pragma unroll
    for (int s = 0; s < 4; ++s){
      const int cb = s*32 + kb*16;
      f16x8 ah  = *reinterpret_cast<const f16x8*>(lb + rA*128 + (cb ^ aswz));
      f16x8 b0h = *reinterpret_cast<const f16x8*>(lb + 16384 + rB0*128 + (cb ^ bswz));
      f16x8 b1h = *reinterpret_cast<const f16x8*>(lb + 16384 + 4096 + rB0*128 + (cb ^ bswz));
      acc0 = __builtin_amdgcn_mfma_f32_32x32x16_f16(ah, b0h, acc0, 0, 0, 0);
      acc1 = __builtin_amdgcn_mfma_f32_32x32x16_f16(ah, b1h, acc1, 0, 0, 0);
    }
    __syncthreads();
  }

  const int col0 = nt*64 + (lane & 31);
  const float b0 = bias[col0], b1 = bias[col0 + 32];
  const int rowBase = wv*32 + 4*kb;
  #pragma unroll
  for (int r = 0; r < 16; ++r){
    const int rr = rowBase + (r & 3) + 8*(r >> 2);
    const size_t o = tb + (size_t)rr*2048 + col0;
    outHi[o]      = (f16)tanhf(acc0[r] + b0);
    outHi[o + 32] = (f16)tanhf(acc1[r] + b1);
  }
}

// ---------------------------------------------------------------------------
// Batched sa GEMM (all t): A = p hi (single pass), W = [Wlow^T|Wup^T].
// nt<32 -> Y (f32, raw); nt>=32 -> G (f16). Grid (64 nt, 64 t), K=2048.
// ---------------------------------------------------------------------------
__global__ __launch_bounds__(256, 2) void k_gemm_full2(
    const f16* __restrict__ aHi,                                // [T][B][2048]
    const f16* __restrict__ wSp,                                // [4096][2048]
    float* __restrict__ Y, f16* __restrict__ G)                 // [T][B][2048]
{
  const int nt = blockIdx.x, t = blockIdx.y;
  const size_t tb = (size_t)t * BD;
  const int tid = threadIdx.x;
  const int lane = tid & 63, wv = tid >> 6;
  __shared__ __align__(16) char lds[49152];
  const f16* wH = wSp + (size_t)(nt*64)*2048;
  const f16* aH = aHi + tb;

  auto stage = [&](int buf, int ki){
    char* lb = lds + buf*24576;
    const int ke = ki*64;
    #pragma unroll
    for (int i = 0; i < 4; ++i){
      const int c = i*256 + tid, row = c >> 3;
      const int srcb = ((c & 7)*16) ^ ((row & 7) << 4);
      g2l16((const char*)(aH + (size_t)row*2048 + ke) + srcb, lb + c*16);
    }
    #pragma unroll
    for (int i = 0; i < 2; ++i){
      const int c = i*256 + tid, row = c >> 3;
      const int srcb = ((c & 7)*16) ^ ((row & 7) << 4);
      g2l16((const char*)(wH + (size_t)row*2048 + ke) + srcb, lb + 16384 + c*16);
    }
  };

  f32x16 acc0, acc1;
  #pragma unroll
  for (int r = 0; r < 16; ++r){ acc0[r] = 0.f; acc1[r] = 0.f; }
  const int rA = wv*32 + (lane & 31);
  const int kb = lane >> 5;
  const int rB0 = lane & 31;
  const int aswz = (rA & 7) << 4;
  const int bswz = (rB0 & 7) << 4;

  stage(0, 0);
  __syncthreads();
  for (int ki = 0; ki < 32; ++ki){
    const int buf = ki & 1;
    if (ki < 31) stage(buf ^ 1, ki + 1);
    const char* lb = lds + buf*24576;
    #pragma unroll
    for (int s = 0; s < 4; ++s){
      const int cb = s*32 + kb*16;
      f16x8 ah  = *reinterpret_cast<const f16x8*>(lb + rA*128 + (cb ^ aswz));
      f16x8 b0h = *reinterpret_cast<const f16x8*>(lb + 16384 + rB0*128 + (cb ^ bswz));
      f16x8 b1h = *reinterpret_cast<const f16x8*>(lb + 16384 + 4096 + rB0*128 + (cb ^ bswz));
      acc0 = __builtin_amdgcn_mfma_f32_32x32x16_f16(ah, b0h, acc0, 0, 0, 0);
      acc1 = __builtin_amdgcn_mfma_f32_32x32x16_f16(ah, b1h, acc1, 0, 0, 0);
    }
    __syncthreads();
  }

  const int col0 = nt*64 + (lane & 31);
  const int rowBase = wv*32 + 4*kb;
  if (nt < 32){
    float* yp = Y + tb + col0;
    #pragma unroll
    for (int r = 0; r < 16; ++r){
      const int rr = rowBase + (r & 3) + 8*(r >> 2);
      yp[(size_t)rr*2048]      = acc0[r];
      yp[(size_t)rr*2048 + 32] = acc1[r];
    }
  } else {
    f16* gp = G + tb + (col0 - 2048);
    #pragma unroll
    for (int r = 0; r < 16; ++r){
      const int rr = rowBase + (r & 3) + 8*(r >> 2);
      gp[(size_t)rr*2048]      = (f16)acc0[r];
      gp[(size_t)rr*2048 + 32] = (f16)acc1[r];
    }
  }
}

// ---------------------------------------------------------------------------
// Self-attention refine chain (persistent over t). Block per b, 1024 threads.
// Scores use hi-only r/p; G rows 0..31 cached in 128KB LDS.
// ---------------------------------------------------------------------------
__global__ __launch_bounds__(1024) void k_selfchain(
    const f16* __restrict__ pHi,                                // [T][B][2048]
    const float* __restrict__ Y, const f16* __restrict__ G,     // [T][B][2048]
    const float* __restrict__ bias,
    f16* __restrict__ rHi, f16* __restrict__ rLo)               // [T][B][2048]
{
  const int b = blockIdx.x;
  const int tid = threadIdx.x, lane = tid & 63, wv = tid >> 6;   // 16 waves
  __shared__ float sc[64];
  __shared__ float a_lds[64];
  __shared__ f16 Gc[32*2048];                  // G rows 0..31, 128 KB
  // preload G cache (rows fully precomputed before this kernel)
  {
    const f16* gsrc = G + (size_t)b*2048;      // row i at G[(i*128+b)*2048]
    for (int i = 0; i < 32; ++i){
      const f16* gr = gsrc + (size_t)i*BD;
      #pragma unroll
      for (int q = 0; q < 2; ++q){
        const int d = tid + q*1024;
        Gc[i*2048 + d] = gr[d];
      }
    }
  }
  const int d0 = tid * 2;
  f32x2v bb = *reinterpret_cast<const f32x2v*>(bias + d0);
  __syncthreads();
  for (int t = 0; t < 64; ++t){
    const size_t pb = ((size_t)t*128 + b)*2048;
    if (t > 0){
      // each wave holds the full p[t] row (32 f32/lane), hi only
      float hreg[32];
      #pragma unroll
      for (int jj = 0; jj < 4; ++jj){
        const int d = (jj*64 + lane)*8;
        f16x8 h8 = *reinterpret_cast<const f16x8*>(pHi + pb + d);
        #pragma unroll
        for (int j = 0; j < 8; ++j) hreg[jj*8+j] = (float)h8[j];
      }
      for (int i = wv; i < t; i += 16){
        const f16* rh = rHi + ((size_t)i*128 + b)*2048;
        float dot = 0.f;
        #pragma unroll
        for (int jj = 0; jj < 4; ++jj){
          const int d = (jj*64 + lane)*8;
          f16x8 h8 = *reinterpret_cast<const f16x8*>(rh + d);
          #pragma unroll
          for (int j = 0; j < 8; ++j)
            dot += (float)h8[j] * hreg[jj*8+j];
        }
        #pragma unroll
        for (int off = 1; off < 64; off <<= 1) dot += __shfl_xor(dot, off);
        if (lane == 0) sc[i] = dot;
      }
      __syncthreads();
      if (tid < 64){
        const float s = (tid < t) ? sc[tid] : -INFINITY;
        float mm = s;
        #pragma unroll
        for (int off = 1; off < 64; off <<= 1) mm = fmaxf(mm, __shfl_xor(mm, off));
        const float e = (tid < t) ? __expf(s - mm) : 0.f;
        float sum = e;
        #pragma unroll
        for (int off = 1; off < 64; off <<= 1) sum += __shfl_xor(sum, off);
        a_lds[tid] = e / sum;
      }
      __syncthreads();
    }
    float y0, y1;
    {
      f32x2v yv = *reinterpret_cast<const f32x2v*>(Y + (size_t)t*BD + (size_t)b*2048 + d0);
      y0 = yv[0] + bb[0];
      y1 = yv[1] + bb[1];
    }
    if (t > 0){
      float z0 = 0.f, z1 = 0.f;
      const int nl = (t < 32) ? t : 32;
      int i = 0;
      // LDS-cached region (rows 0..31)
      for (; i + 1 < nl; i += 2){
        const float a0 = a_lds[i], a1 = a_lds[i+1];
        f16x2 g0 = *reinterpret_cast<const f16x2*>(&Gc[i*2048 + d0]);
        f16x2 g1 = *reinterpret_cast<const f16x2*>(&Gc[(i+1)*2048 + d0]);
        y0 += a0 * (float)g0[0];
        y1 += a0 * (float)g0[1];
        z0 += a1 * (float)g1[0];
        z1 += a1 * (float)g1[1];
      }
      if (i < nl){
        const float a0 = a_lds[i];
        f16x2 g0 = *reinterpret_cast<const f16x2*>(&Gc[i*2048 + d0]);
        y0 += a0 * (float)g0[0];
        y1 += a0 * (float)g0[1];
        ++i;
      }
      // global region (rows 32..t-1)
      for (; i + 1 < t; i += 2){
        const float a0 = a_lds[i], a1 = a_lds[i+1];
        f16x2 g0 = *reinterpret_cast<const f16x2*>(G + ((size_t)i*128 + b)*2048 + d0);
        f16x2 g1 = *reinterpret_cast<const f16x2*>(G + ((size_t)(i+1)*128 + b)*2048 + d0);
        y0 += a0 * (float)g0[0];
        y1 += a0 * (float)g0[1];
        z0 += a1 * (float)g1[0];
        z1 += a1 * (float)g1[1];
      }
      if (i < t){
        const float a0 = a_lds[i];
        f16x2 g0 = *reinterpret_cast<const f16x2*>(G + ((size_t)i*128 + b)*2048 + d0);
        y0 += a0 * (float)g0[0];
        y1 += a0 * (float)g0[1];
      }
      y0 += z0;
      y1 += z1;
    }
    f16x2 hh, ll;
    {
      const float v0 = tanhf(y0);
      const float v1 = tanhf(y1);
      hh[0] = (f16)v0; ll[0] = (f16)(v0 - (float)hh[0]);
      hh[1] = (f16)v1; ll[1] = (f16)(v1 - (float)hh[1]);
    }
    *reinterpret_cast<f16x2*>(rHi + pb + d0) = hh;
    *reinterpret_cast<f16x2*>(rLo + pb + d0) = ll;
    __syncthreads();   // r[t] stores drained before t+1 scores read them
  }
}

// ---------------------------------------------------------------------------
// Head stage 1: z1 = relu(r1(8192x2048) @ hw1 + hb1), single-pass f16 MFMA
// ---------------------------------------------------------------------------
__global__ __launch_bounds__(256) void k_headgemm(
    const f16* __restrict__ aHi,
    const f16* __restrict__ w1H,   // [224][2048]
    const float* __restrict__ hb1,
    float* __restrict__ z1)        // [8192][224]
{
  const int mb = blockIdx.x;
  const int nt = blockIdx.y;
  const int lane = threadIdx.x & 63, wv = threadIdx.x >> 6;
  const int rowA = mb*128 + wv*32 + (lane & 31);
  const int kb = lane >> 5;
  const int n = nt*32 + (lane & 31);
  const f16* pAH = aHi + (size_t)rowA*2048 + kb*8;
  const f16* pBH = w1H + (size_t)n*2048 + kb*8;
  f32x16 acc;
  #pragma unroll
  for (int r = 0; r < 16; ++r) acc[r] = 0.f;
  #pragma unroll 4
  for (int s = 0; s < 128; ++s){
    f16x8 ah = *reinterpret_cast<const f16x8*>(pAH + s*16);
    f16x8 bh = *reinterpret_cast<const f16x8*>(pBH + s*16);
    acc = __builtin_amdgcn_mfma_f32_32x32x16_f16(ah, bh, acc, 0, 0, 0);
  }
  const float bias = (n < 200) ? hb1[n] : 0.f;
  const int rowBase = mb*128 + wv*32 + 4*kb;
  #pragma unroll
  for (int r = 0; r < 16; ++r){
    const int rr = rowBase + (r & 3) + 8*(r >> 2);
    z1[(size_t)rr*224 + n] = fmaxf(acc[r] + bias, 0.f);
  }
}

// Head stage 2
__global__ __launch_bounds__(256) void k_head2(
    const float* __restrict__ z1,
    const float* __restrict__ hw2, const float* __restrict__ hb2,
    const float* __restrict__ hw3, const float* __restrict__ hb3,
    float* __restrict__ out)
{
  const int r0 = blockIdx.x * 64;
  const int tid = threadIdx.x;
  __shared__ float zl[64][200];
  __shared__ float z2[64][50];
  for (int i = tid; i < 64*200; i += 256){
    const int r = i / 200, n = i % 200;
    zl[r][n] = z1[(size_t)(r0 + r)*224 + n];
  }
  __syncthreads();
  for (int i = tid; i < 64*50; i += 256){
    const int r = i / 50, n = i % 50;
    float s = hb2[n];
    for (int k = 0; k < 200; ++k) s += zl[r][k] * hw2[k*50 + n];
    z2[r][n] = fmaxf(s, 0.f);
  }
  __syncthreads();
  for (int i = tid; i < 128; i += 256){
    const int r = i >> 1, c = i & 1;
    float s = hb3[c];
    for (int k = 0; k < 50; ++k) s += z2[r][k] * hw3[k*2 + c];
    const int rg = r0 + r;
    const int tt = rg >> 7, b = rg & 127;
    out[(size_t)b*128 + tt*2 + c] = s;
  }
}

// ---------------------------------------------------------------------------
extern "C" void kernel_launch(void* const* d_in, const int* in_sizes, int n_in,
                              void* d_out, int out_size, void* d_ws, size_t ws_size,
                              hipStream_t stream)
{
  (void)in_sizes; (void)n_in; (void)out_size; (void)ws_size;
  const float* x_flat = (const float*)d_in[0];
  const float* enc    = (const float*)d_in[1];
  const float* h0     = (const float*)d_in[2];
  const float* c0     = (const float*)d_in[3];
  const float* cx_w0  = (const float*)d_in[4];
  const float* cx_b0  = (const float*)d_in[5];
  const float* ch_w0  = (const float*)d_in[6];
  const float* ch_b0  = (const float*)d_in[7];
  const float* cx_w1  = (const float*)d_in[8];
  const float* cx_b1  = (const float*)d_in[9];
  const float* ch_w1  = (const float*)d_in[10];
  const float* ch_b1  = (const float*)d_in[11];
  const float* ia_w0  = (const float*)d_in[12];
  const float* ia_b0  = (const float*)d_in[13];
  const float* sa_w0  = (const float*)d_in[14];
  const float* sa_b0  = (const float*)d_in[15];
  const float* ia_w1  = (const float*)d_in[16];
  const float* ia_b1  = (const float*)d_in[17];
  const float* sa_w1  = (const float*)d_in[18];
  const float* sa_b1  = (const float*)d_in[19];
  const float* hw1    = (const float*)d_in[20];
  const float* hb1    = (const float*)d_in[21];
  const float* hw2    = (const float*)d_in[22];
  const float* hb2    = (const float*)d_in[23];
  const float* hw3    = (const float*)d_in[24];
  const float* hb3    = (const float*)d_in[25];
  float* out = (float*)d_out;

  char* ws = (char*)d_ws;
  size_t off = 0;
  auto alloc = [&](size_t bytes) -> char* {
    char* p = ws + off;
    off += (bytes + 255) & ~(size_t)255;
    return p;
  };
  const size_t WPLANE = (size_t)2048*4096*2;   // 16 MiB
  const size_t TPLANE = (size_t)64*BD*2;       // 32 MiB, [T][B][D] f16
  f16* wIa0 = (f16*)alloc(WPLANE);
  f16* wSa0 = (f16*)alloc(WPLANE);   // [4096][2048]: Wlow^T rows 0..2047, Wup^T rows 2048..
  f16* wIa1 = (f16*)alloc(WPLANE);
  f16* wSa1 = (f16*)alloc(WPLANE);
  f16* w1H  = (f16*)alloc((size_t)224*2048*2);
  f16* encF = (f16*)alloc((size_t)128*128*2048*2);   // 64 MiB
  f16* encT = (f16*)alloc((size_t)128*2048*128*2);   // 64 MiB
  f16* S1 = (f16*)alloc(TPLANE);
  f16* S2 = (f16*)alloc(TPLANE);
  f16* S3 = (f16*)alloc(TPLANE);
  f16* S4 = (f16*)alloc(TPLANE);
  f16* S5 = (f16*)alloc(TPLANE);
  f16* S6 = (f16*)alloc(TPLANE);
  f16* S7 = (f16*)alloc(TPLANE);
  f16* S8 = (f16*)alloc(TPLANE);
  unsigned short* wh16  = (unsigned short*)alloc((size_t)96*128*2);
  unsigned short* wcx16 = (unsigned short*)alloc((size_t)96*128*2);
  f16* w0h16 = (f16*)alloc((size_t)96*128*2);
  // total ws ~= 449 MiB. Alias names (lifetimes verified disjoint):
  f16*  hr0AHi = S1;                         // layer-0 raw h (hi only)
  f16*  ctx0Hi = S3;
  f16*  p0Hi   = S5;
  float* Y0 = (float*)S1;                    // 64 MiB over S1+S2 (contiguous)
  f16*  G0  = S3;
  f16*  r0Hi = S7;    f16* r0Lo   = S8;
  f16*  xgb  = S1;                           // 128 MiB over S1..S4 (contiguous);
                                             // live [k_xconv, k_cell1_all] only
  f16*  hrw1Hi = S5;                         // hi only
  f16*  ctx1Hi = S1;
  f16*  p1Hi = S7;
  float* Y1 = (float*)S1;                    // 64 MiB over S1+S2
  f16*  G1  = S4;
  f16*  r1Hi = S5;    f16* r1Lo   = S3;
  float* z1 = (float*)wSa0;                  // head scratch (wSa0 dead by then)

  // ---- prologue -----------------------------------------------------------
  k_transpose_f16<<<dim3(64,128),256,0,stream>>>(ia_w0, wIa0, 4096, 2048);
  k_transpose_f16<<<dim3(64,128),256,0,stream>>>(ia_w1, wIa1, 4096, 2048);
  k_transpose_f16<<<dim3(64,64),256,0,stream>>>(sa_w0, wSa0, 2048, 2048);
  k_transpose_f16<<<dim3(64,64),256,0,stream>>>(sa_w0 + (size_t)2048*2048,
                                                wSa0 + (size_t)2048*2048, 2048, 2048);
  k_transpose_f16<<<dim3(64,64),256,0,stream>>>(sa_w1, wSa1, 2048, 2048);
  k_transpose_f16<<<dim3(64,64),256,0,stream>>>(sa_w1 + (size_t)2048*2048,
                                                wSa1 + (size_t)2048*2048, 2048, 2048);
  k_transpose_f16<<<dim3(7,64),256,0,stream>>>(hw1, w1H, 2048, 200);
  k_enc_prep<<<dim3(64,4,128),256,0,stream>>>(enc, encF, encT);
  k_pack_cellw<<<16,256,0,stream>>>(ch_w1, cx_w1, wh16, wcx16);
  k_pack_cellw0<<<16,256,0,stream>>>(ch_w0, w0h16);

  // ---- layer 0 (fully batched + one persistent chain) ---------------------
  k_cell0<<<1024,256,0,stream>>>(x_flat, h0, c0, cx_w0, cx_b0, w0h16, ch_b0,
                                 hr0AHi);
  k_attn<<<dim3(128,2),256,0,stream>>>(encF, encT, hr0AHi, ctx0Hi);
  k_gemm_full<<<dim3(32,64),256,0,stream>>>(hr0AHi, ctx0Hi,
                                            wIa0, ia_b0, p0Hi);
  k_gemm_full2<<<dim3(64,64),256,0,stream>>>(p0Hi, wSa0, Y0, G0);
  k_selfchain<<<128,1024,0,stream>>>(p0Hi, Y0, G0, sa_b0, r0Hi, r0Lo);

  // ---- layer 1: grid-parallel x-conv, persistent h-cell, batched rest -----
  k_xconv<<<dim3(1024,8),256,0,stream>>>(r0Hi, r0Lo, wcx16, xgb);
  k_cell1_all<<<1024,256,0,stream>>>(xgb,
                                     h0 + (size_t)128*2048, c0 + (size_t)128*2048,
                                     wh16, cx_b1, ch_b1, hrw1Hi);
  k_attn<<<dim3(128,2),256,0,stream>>>(encF, encT, hrw1Hi, ctx1Hi);
  k_gemm_full<<<dim3(32,64),256,0,stream>>>(hrw1Hi, ctx1Hi,
                                            wIa1, ia_b1, p1Hi);
  k_gemm_full2<<<dim3(64,64),256,0,stream>>>(p1Hi, wSa1, Y1, G1);
  k_selfchain<<<128,1024,0,stream>>>(p1Hi, Y1, G1, sa_b1, r1Hi, r1Lo);

  // ---- head (batched over all t,b) ----------------------------------------
  k_headgemm<<<dim3(64,7),256,0,stream>>>(r1Hi, w1H, hb1, z1);
  k_head2<<<128,256,0,stream>>>(z1, hw2, hb2, hw3, hb3, out);
}